// Round 7
// baseline (1250.300 us; speedup 1.0000x reference)
//
#include <hip/hip_runtime.h>
#include <hip/hip_bf16.h>
#include <math.h>

typedef __bf16 bf16;
typedef __bf16 bf16x8 __attribute__((ext_vector_type(8)));
typedef float  f32x4  __attribute__((ext_vector_type(4)));
typedef unsigned int u32;

#define DMODEL 1536
#define NHEADS 12
#define HD 128
#define HDH 64

__device__ __forceinline__ void async16(const void* g, void* l) {
  __builtin_amdgcn_global_load_lds((const __attribute__((address_space(1))) u32*)g,
                                   (__attribute__((address_space(3))) u32*)l, 16, 0, 0);
}

// ---------------- block reduction (block = 256) ----------------
__device__ inline void block_reduce2(float& a, float& b) {
  __shared__ float sa[4], sb[4];
  #pragma unroll
  for (int off = 32; off; off >>= 1) {
    a += __shfl_xor(a, off);
    b += __shfl_xor(b, off);
  }
  int w = threadIdx.x >> 6;
  if ((threadIdx.x & 63) == 0) { sa[w] = a; sb[w] = b; }
  __syncthreads();
  a = sa[0] + sa[1] + sa[2] + sa[3];
  b = sb[0] + sb[1] + sb[2] + sb[3];
  __syncthreads();
}

// ---------------- LayerNorm (+AdaLN modulate), phase-1 only ----------------
__global__ __launch_bounds__(256)
void ln_kernel(const float* __restrict__ X, bf16* __restrict__ Y,
               const float* __restrict__ sst, const float* __restrict__ temb,
               int jshift, int jscale, int FS)
{
  int row = blockIdx.x;
  const float* x = X + (size_t)row * DMODEL;
  float v[6];
  float s1 = 0.f, s2 = 0.f;
  #pragma unroll
  for (int i = 0; i < 6; i++) {
    float t = x[threadIdx.x + i * 256];
    v[i] = t; s1 += t; s2 += t * t;
  }
  block_reduce2(s1, s2);
  float mean = s1 * (1.f / DMODEL);
  float var  = s2 * (1.f / DMODEL) - mean * mean;
  float rs = rsqrtf(var + 1e-6f);
  int f = row / FS;
  bf16* y = Y + (size_t)row * DMODEL;
  #pragma unroll
  for (int i = 0; i < 6; i++) {
    int d = threadIdx.x + i * 256;
    float t = (v[i] - mean) * rs;
    float sc = sst[jscale * DMODEL + d] + temb[(f * 6 + jscale) * DMODEL + d];
    float sh = sst[jshift * DMODEL + d] + temb[(f * 6 + jshift) * DMODEL + d];
    y[d] = (bf16)(t * (1.f + sc) + sh);
  }
}

// ---------------- RMSNorm (+ optional RoPE), dual-mode input ----------------
__global__ __launch_bounds__(256)
void rms_rope_kernel(const float* __restrict__ P, int S, long long MN,
                     const bf16* __restrict__ Xb, int RS, int CO,
                     const float* __restrict__ bias, bf16* __restrict__ Y,
                     const float* __restrict__ w,
                     const float* __restrict__ cosb, const float* __restrict__ sinb,
                     int dorope, float oscale)
{
  __shared__ float rowbuf[DMODEL];
  int row = blockIdx.x;
  float v[6];
  float s2 = 0.f, dummy = 0.f;
  if (Xb) {
    const bf16* x = Xb + (size_t)row * RS + CO;
    #pragma unroll
    for (int i = 0; i < 6; i++) {
      int d = threadIdx.x + i * 256;
      float t = (float)x[d];
      v[i] = t; rowbuf[d] = t; s2 += t * t;
    }
  } else {
    const float* x = P + (size_t)row * RS + CO;
    #pragma unroll
    for (int i = 0; i < 6; i++) {
      int d = threadIdx.x + i * 256;
      float t = bias[d];
      for (int s = 0; s < S; s++) t += x[(size_t)s * MN + d];
      v[i] = t; rowbuf[d] = t; s2 += t * t;
    }
  }
  __syncthreads();
  block_reduce2(s2, dummy);
  float rs = rsqrtf(s2 * (1.f / DMODEL) + 1e-6f) * oscale;
  bf16* y = Y + (size_t)row * DMODEL;
  if (dorope) {
    #pragma unroll
    for (int i = 0; i < 3; i++) {
      int p = threadIdx.x + i * 256;
      int d0 = 2 * p, d1 = 2 * p + 1;
      float y0 = rowbuf[d0] * rs * w[d0];
      float y1 = rowbuf[d1] * rs * w[d1];
      int ih = p & 63;
      float c = cosb[(size_t)row * HDH + ih];
      float s = sinb[(size_t)row * HDH + ih];
      y[d0] = (bf16)(y0 * c - y1 * s);
      y[d1] = (bf16)(y0 * s + y1 * c);
    }
  } else {
    #pragma unroll
    for (int i = 0; i < 6; i++) {
      int d = threadIdx.x + i * 256;
      y[d] = (bf16)(v[i] * rs * w[d]);
    }
  }
}

// ---------------- fused q+k RMSNorm+RoPE (one launch for both) ----------------
__global__ __launch_bounds__(256)
void rmsrope_qk_kernel(const bf16* __restrict__ Xb, int RS,
                       bf16* __restrict__ Q, bf16* __restrict__ Kb,
                       const float* __restrict__ wq, const float* __restrict__ wk,
                       const float* __restrict__ cosb, const float* __restrict__ sinb,
                       float qscale)
{
  __shared__ float rowbuf[DMODEL];
  int row = blockIdx.x;
  for (int pass = 0; pass < 2; ++pass) {
    const bf16* x = Xb + (size_t)row * RS + (pass ? DMODEL : 0);
    const float* wv = pass ? wk : wq;
    bf16* y = (pass ? Kb : Q) + (size_t)row * DMODEL;
    float osc = pass ? 1.0f : qscale;
    float s2 = 0.f, dmy = 0.f;
    #pragma unroll
    for (int i = 0; i < 6; i++) {
      int d = threadIdx.x + i * 256;
      float t = (float)x[d];
      rowbuf[d] = t; s2 += t * t;
    }
    __syncthreads();
    block_reduce2(s2, dmy);
    float rs = rsqrtf(s2 * (1.f / DMODEL) + 1e-6f) * osc;
    #pragma unroll
    for (int i = 0; i < 3; i++) {
      int p = threadIdx.x + i * 256;
      int d0 = 2 * p, d1 = 2 * p + 1;
      float y0 = rowbuf[d0] * rs * wv[d0];
      float y1 = rowbuf[d1] * rs * wv[d1];
      int ih = p & 63;
      float c = cosb[(size_t)row * HDH + ih];
      float s = sinb[(size_t)row * HDH + ih];
      y[d0] = (bf16)(y0 * c - y1 * s);
      y[d1] = (bf16)(y0 * s + y1 * c);
    }
    __syncthreads();
  }
}

// ---------------- weight transpose+cast: W (K,N) fp32 -> Wt (N,K) bf16 ----------------
__global__ __launch_bounds__(256)
void wt_kernel(const float* __restrict__ W, bf16* __restrict__ Wt, int K, int N)
{
  __shared__ float T[32][33];
  int k0 = blockIdx.x * 32, n0 = blockIdx.y * 32;
  int tx = threadIdx.x & 31, ty = threadIdx.x >> 5;
  #pragma unroll
  for (int i = 0; i < 4; i++)
    T[ty + 8 * i][tx] = W[(size_t)(k0 + ty + 8 * i) * N + n0 + tx];
  __syncthreads();
  #pragma unroll
  for (int i = 0; i < 4; i++)
    Wt[(size_t)(n0 + ty + 8 * i) * K + k0 + tx] = (bf16)T[tx][ty + 8 * i];
}

// ---------------- bias concat ----------------
__global__ __launch_bounds__(256)
void catbias_kernel(float* __restrict__ bqkv, const float* __restrict__ bq,
                    const float* __restrict__ bk, const float* __restrict__ bv,
                    float* __restrict__ cbkv, const float* __restrict__ cbk,
                    const float* __restrict__ cbv)
{
  int i = blockIdx.x * 256 + threadIdx.x;
  if (i < DMODEL) {
    bqkv[i] = bq[i]; bqkv[DMODEL + i] = bk[i]; bqkv[2 * DMODEL + i] = bv[i];
    cbkv[i] = cbk[i]; cbkv[DMODEL + i] = cbv[i];
  }
}

// ---------------- GEMM m97-style 128^2 (kept for small-grid ckv) ----------------
__global__ __launch_bounds__(256)
void gemm_bt(const bf16* __restrict__ A, const bf16* __restrict__ Bt,
             const float* __restrict__ bias, float* __restrict__ Cf,
             bf16* __restrict__ Cb, int M, int N, int K, int act,
             int Ks, long long MN)
{
  __shared__ bf16 As[128 * 32];
  __shared__ bf16 Bs[128 * 32];
  int tid = threadIdx.x, lane = tid & 63, w = tid >> 6;
  int wm = w >> 1, wn = w & 1;
  int l16 = lane & 15, quad = lane >> 4;

  int gx = (M + 127) >> 7, gy = N >> 7;
  int per_panel = gx << 3;
  int bid = blockIdx.x;
  int panel = bid / per_panel;
  int rem = bid - panel * per_panel;
  int pc0 = panel << 3;
  int ncols = gy - pc0; if (ncols > 8) ncols = 8;
  int by = pc0 + rem % ncols;
  int bx = rem / ncols;
  int bm = bx * 128, bn = by * 128;

  int kb0 = blockIdx.y * Ks;

  int rl = lane >> 2;
  int kk = (lane & 3) * 8;
  int r0 = (2 * w) * 16 + rl, r1 = (2 * w + 1) * 16 + rl;
  int am0 = bm + r0; if (am0 > M - 1) am0 = M - 1;
  int am1 = bm + r1; if (am1 > M - 1) am1 = M - 1;
  const bf16* a0 = A + (size_t)am0 * K + kk;
  const bf16* a1 = A + (size_t)am1 * K + kk;
  const bf16* b0 = Bt + (size_t)(bn + r0) * K + kk;
  const bf16* b1 = Bt + (size_t)(bn + r1) * K + kk;
  bf16* lA0 = As + (2 * w) * 512; bf16* lA1 = As + (2 * w + 1) * 512;
  bf16* lB0 = Bs + (2 * w) * 512; bf16* lB1 = Bs + (2 * w + 1) * 512;

  f32x4 acc[4][4] = {};
  int kend = kb0 + Ks;
  for (int k0 = kb0; k0 < kend; k0 += 32) {
    async16(a0 + k0, lA0);
    async16(a1 + k0, lA1);
    async16(b0 + k0, lB0);
    async16(b1 + k0, lB1);
    __syncthreads();
    bf16x8 af[4], bfv[4];
    #pragma unroll
    for (int mi = 0; mi < 4; mi++)
      af[mi] = *(const bf16x8*)&As[(wm * 64 + mi * 16 + l16) * 32 + quad * 8];
    #pragma unroll
    for (int ni = 0; ni < 4; ni++)
      bfv[ni] = *(const bf16x8*)&Bs[(wn * 64 + ni * 16 + l16) * 32 + quad * 8];
    #pragma unroll
    for (int mi = 0; mi < 4; mi++)
      #pragma unroll
      for (int ni = 0; ni < 4; ni++)
        acc[mi][ni] = __builtin_amdgcn_mfma_f32_16x16x32_bf16(af[mi], bfv[ni], acc[mi][ni], 0, 0, 0);
    __syncthreads();
  }
  float* Cfo = Cf ? Cf + (size_t)blockIdx.y * MN : nullptr;
  #pragma unroll
  for (int mi = 0; mi < 4; mi++) {
    #pragma unroll
    for (int r = 0; r < 4; r++) {
      int m = bm + wm * 64 + mi * 16 + quad * 4 + r;
      if (m < M) {
        #pragma unroll
        for (int ni = 0; ni < 4; ni++) {
          int n = bn + wn * 64 + ni * 16 + l16;
          float val = acc[mi][ni][r] + (bias ? bias[n] : 0.f);
          if (act == 1) {
            float u = val + 0.044715f * val * val * val;
            float z = 1.5957691216057308f * u;
            val = val / (1.f + __expf(-z));
          }
          if (Cfo) Cfo[(size_t)m * N + n] = val;
          else     Cb[(size_t)m * N + n] = (bf16)val;
        }
      }
    }
  }
}

// ---------------- GEMM 256^2, BK=32, 4-deep circular buffer (R4-best) ----------
__global__ __launch_bounds__(512, 2)
void gemm256(const bf16* __restrict__ A, const bf16* __restrict__ Bt,
             const float* __restrict__ bias, float* __restrict__ Cf,
             bf16* __restrict__ Cb, int M, int N, int K, int act,
             int S, long long MN)
{
  __shared__ bf16 LDS[4][2][16 * 512];  // [buf][0=A,1=B][8192 bf16 = 16KB]
  int tid = threadIdx.x, lane = tid & 63, w = tid >> 6;
  int wm = w >> 2, wn = w & 3;
  int l16 = lane & 15, quad = lane >> 4;

  int gmx = (M + 255) >> 8, gny = N >> 8;
  int per_panel = gmx << 3;
  int bid = blockIdx.x;
  int panel = bid / per_panel;
  int rem = bid - panel * per_panel;
  int pc0 = panel << 3;
  int ncols = gny - pc0; if (ncols > 8) ncols = 8;
  int by = pc0 + rem % ncols;
  int bx = rem / ncols;
  int bm = bx << 8, bn = by << 8;

  int NTtot = K >> 5;
  int sidx = blockIdx.y;
  int basek = NTtot / S, remk = NTtot % S;
  int NT = basek + (sidx < remk ? 1 : 0);
  int t0k = sidx * basek + (sidx < remk ? sidx : remk);
  int kb0 = t0k << 5;

  int aro = (l16 * 64 + quad * 16) ^ ((l16 >> 3) << 5);
  char* ldsb = (char*)&LDS[0][0][0];   // buffer stride 32768B; B at +16384

  int srl = lane >> 2;
  int sc16 = (lane & 3) ^ (((lane >> 5) & 1) << 1);
  int Mm1 = M - 1, Nm1 = N - 1;
  int ga0 = bm + w * 16 + srl;        if (ga0 > Mm1) ga0 = Mm1;
  int ga1 = bm + 128 + w * 16 + srl;  if (ga1 > Mm1) ga1 = Mm1;
  int gb0 = bn + w * 16 + srl;        if (gb0 > Nm1) gb0 = Nm1;
  int gb1 = bn + 128 + w * 16 + srl;  if (gb1 > Nm1) gb1 = Nm1;
  const bf16* Ag0 = A + (size_t)ga0 * K + kb0 + sc16 * 8;
  const bf16* Ag1 = A + (size_t)ga1 * K + kb0 + sc16 * 8;
  const bf16* Bg0 = Bt + (size_t)gb0 * K + kb0 + sc16 * 8;
  const bf16* Bg1 = Bt + (size_t)gb1 * K + kb0 + sc16 * 8;

#define STG(tt) do { int _k = (tt) * 32; char* _d = ldsb + ((tt) & 3) * 32768 + w * 1024; \
    async16(Ag0 + _k, _d);          async16(Ag1 + _k, _d + 8192); \
    async16(Bg0 + _k, _d + 16384);  async16(Bg1 + _k, _d + 24576); } while (0)
#define MFMA_(d, a, b) d = __builtin_amdgcn_mfma_f32_16x16x32_bf16(a, b, d, 0, 0, 0)

  STG(0);
  if (NT > 1) STG(1);
  if (NT > 2) STG(2);
  if (NT > 2)      { asm volatile("s_waitcnt vmcnt(8)" ::: "memory"); }
  else if (NT > 1) { asm volatile("s_waitcnt vmcnt(4)" ::: "memory"); }
  else             { asm volatile("s_waitcnt vmcnt(0)" ::: "memory"); }
  __builtin_amdgcn_s_barrier();

  f32x4 acc[8][4] = {};
  for (int t = 0; t < NT; ++t) {
    if (t + 3 < NT) STG(t + 3);
    const char* Ar = ldsb + (t & 3) * 32768 + wm * 8192 + aro;
    const char* Br = ldsb + (t & 3) * 32768 + 16384 + wn * 4096 + aro;
    bf16x8 a[8], bv[4];
    #pragma unroll
    for (int i = 0; i < 4; i++) bv[i] = *(const bf16x8*)(Br + i * 1024);
    #pragma unroll
    for (int i = 0; i < 8; i++) a[i] = *(const bf16x8*)(Ar + i * 1024);
    #pragma unroll
    for (int mi = 0; mi < 8; mi++)
      #pragma unroll
      for (int ni = 0; ni < 4; ni++)
        MFMA_(acc[mi][ni], a[mi], bv[ni]);
    int remt = NT - 1 - t;
    if (remt >= 3)      { asm volatile("s_waitcnt vmcnt(8)" ::: "memory"); __builtin_amdgcn_s_barrier(); }
    else if (remt == 2) { asm volatile("s_waitcnt vmcnt(4)" ::: "memory"); __builtin_amdgcn_s_barrier(); }
    else if (remt == 1) { asm volatile("s_waitcnt vmcnt(0)" ::: "memory"); __builtin_amdgcn_s_barrier(); }
  }
#undef STG
#undef MFMA_

  float* Cfo = Cf ? Cf + (size_t)blockIdx.y * MN : nullptr;
  #pragma unroll
  for (int mi = 0; mi < 8; mi++) {
    #pragma unroll
    for (int r = 0; r < 4; r++) {
      int m = bm + wm * 128 + mi * 16 + quad * 4 + r;
      if (m < M) {
        #pragma unroll
        for (int ni = 0; ni < 4; ni++) {
          int n = bn + wn * 64 + ni * 16 + l16;
          float val = acc[mi][ni][r] + (bias ? bias[n] : 0.f);
          if (act == 1) {
            float u = val + 0.044715f * val * val * val;
            float z = 1.5957691216057308f * u;
            val = val / (1.f + __expf(-z));
          }
          if (Cfo) Cfo[(size_t)m * N + n] = val;
          else     Cb[(size_t)m * N + n] = (bf16)val;
        }
      }
    }
  }
}

// ---------------- V transpose from bf16 source (bias pre-applied) ----------------
__global__ __launch_bounds__(256)
void transposev_kernel(const bf16* __restrict__ Xb, int RS, int CO,
                       bf16* __restrict__ Vt, int L)
{
  __shared__ bf16 T[64][65];
  int l0 = blockIdx.x * 64, n0 = blockIdx.y * 64;
  int tid = threadIdx.x;
  int r = tid >> 2;
  int c8 = (tid & 3) * 16;
  int lc = l0 + r; if (lc > L - 1) lc = L - 1;
  const bf16* src = Xb + (size_t)lc * RS + CO + n0 + c8;
  #pragma unroll
  for (int i = 0; i < 16; i++) T[r][c8 + i] = src[i];
  __syncthreads();
  #pragma unroll
  for (int i = 0; i < 16; i++) {
    int l = l0 + c8 + i;
    if (l < L) Vt[(size_t)(n0 + r) * L + l] = T[c8 + i][r];
  }
}

// ---------------- flash attention: 64-q blocks, 4 waves + T13 defer-max ----------
__global__ __launch_bounds__(256)
void flash2_kernel(const bf16* __restrict__ Q, const bf16* __restrict__ Kg,
                   const bf16* __restrict__ Vt, bf16* __restrict__ O,
                   int Lq, int Lk, int FS, int causal, int nqb)
{
  __shared__ bf16 Kt[64 * 128];
  __shared__ bf16 Vtile[128 * 64];
  __shared__ bf16 Pl[4][16][72];
  int tid = threadIdx.x, lane = tid & 63, w = tid >> 6;
  int l16 = lane & 15, quad = lane >> 4;
  int bid = blockIdx.x;
  int h = bid % NHEADS;
  int qb = nqb - 1 - (bid / NHEADS);
  int q0b = qb * 64;
  int q0w = q0b + w * 16;

  int qrow = q0w + l16; if (qrow > Lq - 1) qrow = Lq - 1;
  const bf16* qbase = Q + (size_t)qrow * DMODEL + h * HD + quad * 8;
  bf16x8 qf[4];
  #pragma unroll
  for (int dc = 0; dc < 4; dc++) qf[dc] = *(const bf16x8*)(qbase + dc * 32);

  int kvrow[4];
  int kvmin_w = Lk, kv_end = Lk;
  if (causal) {
    #pragma unroll
    for (int r = 0; r < 4; r++) {
      int qr = q0w + quad * 4 + r; if (qr > Lq - 1) qr = Lq - 1;
      kvrow[r] = (qr / FS + 1) * FS;
    }
    int q0c = q0w; if (q0c > Lq - 1) q0c = Lq - 1;
    kvmin_w = (q0c / FS + 1) * FS;
    int qlast = q0b + 63; if (qlast > Lq - 1) qlast = Lq - 1;
    kv_end = (qlast / FS + 1) * FS;
    if (kv_end > Lk) kv_end = Lk;
  }

  f32x4 acc_o[8] = {};
  float m_i[4], l_i[4];
  #pragma unroll
  for (int r = 0; r < 4; r++) { m_i[r] = -1e30f; l_i[r] = 0.f; }

  for (int kb = 0; kb < kv_end; kb += 64) {
    #pragma unroll
    for (int j = 0; j < 4; j++) {
      int u = w * 256 + j * 64 + lane;
      int row = u >> 4;
      int c = (u & 15) ^ (row & 15);
      int krow = kb + row; if (krow > Lk - 1) krow = Lk - 1;
      async16(Kg + (size_t)krow * DMODEL + h * HD + c * 8,
              Kt + (size_t)(w * 256 + j * 64) * 8);
    }
    #pragma unroll
    for (int j = 0; j < 4; j++) {
      int u = w * 256 + j * 64 + lane;
      int row = u >> 3;
      int c = (u & 7) ^ (row & 7);
      async16(Vt + (size_t)(h * HD + row) * Lk + kb + c * 8,
              Vtile + (size_t)(w * 256 + j * 64) * 8);
    }
    __syncthreads();

    f32x4 s[4] = {};
    #pragma unroll
    for (int nk = 0; nk < 4; nk++) {
      #pragma unroll
      for (int dc = 0; dc < 4; dc++) {
        bf16x8 kf = *(const bf16x8*)&Kt[(((nk * 16 + l16) << 4) + ((4 * dc + quad) ^ l16)) * 8];
        s[nk] = __builtin_amdgcn_mfma_f32_16x16x32_bf16(qf[dc], kf, s[nk], 0, 0, 0);
      }
    }

    bool need_mask = causal && (kb + 64 > kvmin_w);
    float p[4][4];
    #pragma unroll
    for (int r = 0; r < 4; r++) {
      #pragma unroll
      for (int nk = 0; nk < 4; nk++) {
        float sv = s[nk][r];
        if (need_mask && (kb + nk * 16 + l16 >= kvrow[r])) sv = -1e30f;
        p[nk][r] = sv;
      }
      float bm = fmaxf(fmaxf(p[0][r], p[1][r]), fmaxf(p[2][r], p[3][r]));
      #pragma unroll
      for (int off = 8; off; off >>= 1) bm = fmaxf(bm, __shfl_xor(bm, off));
      // T13 defer-max: skip O-rescale while tile max stays within 8 of running max.
      // P = exp(s - m_old) <= e^8 — safe in f32 accum / bf16 P storage.
      bool resc = (bm > m_i[r] + 8.f);
      float mn = resc ? bm : m_i[r];
      float ps = 0.f;
      #pragma unroll
      for (int nk = 0; nk < 4; nk++) {
        float e = __expf(p[nk][r] - mn);
        p[nk][r] = e; ps += e;
      }
      #pragma unroll
      for (int off = 8; off; off >>= 1) ps += __shfl_xor(ps, off);
      if (resc) {
        float alpha = __expf(m_i[r] - mn);
        m_i[r] = mn;
        l_i[r] = l_i[r] * alpha + ps;
        #pragma unroll
        for (int t = 0; t < 8; t++) acc_o[t][r] *= alpha;
      } else {
        l_i[r] += ps;
      }
    }

    #pragma unroll
    for (int nk = 0; nk < 4; nk++)
      #pragma unroll
      for (int r = 0; r < 4; r++)
        Pl[w][quad * 4 + r][nk * 16 + l16] = (bf16)p[nk][r];
    __threadfence_block();
    bf16x8 pf0 = *(const bf16x8*)&Pl[w][l16][quad * 8];
    bf16x8 pf1 = *(const bf16x8*)&Pl[w][l16][32 + quad * 8];

    #pragma unroll
    for (int t = 0; t < 8; t++) {
      bf16x8 vf0 = *(const bf16x8*)&Vtile[(((t * 16 + l16) << 3) + ((quad) ^ (l16 & 7))) * 8];
      bf16x8 vf1 = *(const bf16x8*)&Vtile[(((t * 16 + l16) << 3) + ((4 + quad) ^ (l16 & 7))) * 8];
      acc_o[t] = __builtin_amdgcn_mfma_f32_16x16x32_bf16(pf0, vf0, acc_o[t], 0, 0, 0);
      acc_o[t] = __builtin_amdgcn_mfma_f32_16x16x32_bf16(pf1, vf1, acc_o[t], 0, 0, 0);
    }
    __syncthreads();
  }

  #pragma unroll
  for (int r = 0; r < 4; r++) {
    int m = q0w + quad * 4 + r;
    if (m < Lq) {
      float inv = 1.f / l_i[r];
      bf16* obase = O + (size_t)m * DMODEL + h * HD;
      #pragma unroll
      for (int t = 0; t < 8; t++)
        obase[t * 16 + l16] = (bf16)(acc_o[t][r] * inv);
    }
  }
}

// ---------------- fused: split-K reduce + gated residual + affine LN ----------------
__global__ __launch_bounds__(256)
void modresid_ln_kernel(const float* __restrict__ base, const float* __restrict__ P,
                        int S, long long MN, const float* __restrict__ bias,
                        float* __restrict__ hout,
                        const float* __restrict__ sst, const float* __restrict__ temb,
                        int jg, int FS,
                        const float* __restrict__ g2, const float* __restrict__ b2,
                        bf16* __restrict__ nh)
{
  int row = blockIdx.x;
  int f = row / FS;
  float v[6]; float s1 = 0.f, s2 = 0.f;
  #pragma unroll
  for (int i = 0; i < 6; i++) {
    int d = threadIdx.x + i * 256;
    long long idx = (size_t)row * DMODEL + d;
    float gg = sst[jg * DMODEL + d] + temb[(f * 6 + jg) * DMODEL + d];
    float t = bias[d];
    for (int s = 0; s < S; s++) t += P[(size_t)s * MN + idx];
    float hv = base[idx] + t * gg;
    hout[idx] = hv;
    v[i] = hv; s1 += hv; s2 += hv * hv;
  }
  block_reduce2(s1, s2);
  float mean = s1 * (1.f / DMODEL);
  float var  = s2 * (1.f / DMODEL) - mean * mean;
  float rs = rsqrtf(var + 1e-6f);
  bf16* y = nh + (size_t)row * DMODEL;
  #pragma unroll
  for (int i = 0; i < 6; i++) {
    int d = threadIdx.x + i * 256;
    y[d] = (bf16)((v[i] - mean) * rs * g2[d] + b2[d]);
  }
}

// ---------------- fused: split-K reduce + residual + AdaLN-mod LN ----------------
__global__ __launch_bounds__(256)
void addf_ln_kernel(float* __restrict__ hbuf, const float* __restrict__ P,
                    int S, long long MN, const float* __restrict__ bias,
                    const float* __restrict__ sst, const float* __restrict__ temb,
                    int jshift, int jscale, int FS, bf16* __restrict__ nh)
{
  int row = blockIdx.x;
  int f = row / FS;
  float v[6]; float s1 = 0.f, s2 = 0.f;
  #pragma unroll
  for (int i = 0; i < 6; i++) {
    int d = threadIdx.x + i * 256;
    long long idx = (size_t)row * DMODEL + d;
    float t = bias[d];
    for (int s = 0; s < S; s++) t += P[(size_t)s * MN + idx];
    float hv = hbuf[idx] + t;
    hbuf[idx] = hv;
    v[i] = hv; s1 += hv; s2 += hv * hv;
  }
  block_reduce2(s1, s2);
  float mean = s1 * (1.f / DMODEL);
  float var  = s2 * (1.f / DMODEL) - mean * mean;
  float rs = rsqrtf(var + 1e-6f);
  bf16* y = nh + (size_t)row * DMODEL;
  #pragma unroll
  for (int i = 0; i < 6; i++) {
    int d = threadIdx.x + i * 256;
    float t = (v[i] - mean) * rs;
    float sc = sst[jscale * DMODEL + d] + temb[(f * 6 + jscale) * DMODEL + d];
    float sh = sst[jshift * DMODEL + d] + temb[(f * 6 + jshift) * DMODEL + d];
    y[d] = (bf16)(t * (1.f + sc) + sh);
  }
}

// ---------------- elementwise (final split-K reduce + gated residual) ----------------
__global__ __launch_bounds__(256)
void modresid_kernel(const float* __restrict__ base, const float* __restrict__ P,
                     int S, long long MN, const float* __restrict__ bias,
                     float* __restrict__ out,
                     const float* __restrict__ sst, const float* __restrict__ temb,
                     int jg, int FS, long long total)
{
  long long i = (long long)blockIdx.x * 256 + threadIdx.x;
  if (i >= total) return;
  int d = (int)(i % DMODEL);
  int f = (int)((i / DMODEL) / FS);
  float g = sst[jg * DMODEL + d] + temb[(f * 6 + jg) * DMODEL + d];
  float v = bias[d];
  for (int s = 0; s < S; s++) v += P[(size_t)s * MN + i];
  out[i] = base[i] + v * g;
}

__global__ __launch_bounds__(256)
void cast_kernel(const float* __restrict__ x, bf16* __restrict__ y, long long total)
{
  long long i = (long long)blockIdx.x * 256 + threadIdx.x;
  if (i < total) y[i] = (bf16)x[i];
}

// ---------------- orchestration ----------------
extern "C" void kernel_launch(void* const* d_in, const int* in_sizes, int n_in,
                              void* d_out, int out_size, void* d_ws, size_t ws_size,
                              hipStream_t stream)
{
  const float* hs   = (const float*)d_in[0];
  const float* enc  = (const float*)d_in[1];
  const float* temb = (const float*)d_in[2];
  const float* cosb = (const float*)d_in[3];
  const float* sinb = (const float*)d_in[4];
  const float* sst  = (const float*)d_in[6];
  const float* wq = (const float*)d_in[7];
  const float* wk = (const float*)d_in[8];
  const float* wv = (const float*)d_in[9];
  const float* wo = (const float*)d_in[10];
  const float* bq = (const float*)d_in[11];
  const float* bk = (const float*)d_in[12];
  const float* bv = (const float*)d_in[13];
  const float* bo = (const float*)d_in[14];
  const float* nq_w = (const float*)d_in[15];
  const float* nk_w = (const float*)d_in[16];
  const float* ln2_g = (const float*)d_in[17];
  const float* ln2_b = (const float*)d_in[18];
  const float* cwq = (const float*)d_in[19];
  const float* cwk = (const float*)d_in[20];
  const float* cwv = (const float*)d_in[21];
  const float* cwo = (const float*)d_in[22];
  const float* cbq = (const float*)d_in[23];
  const float* cbk = (const float*)d_in[24];
  const float* cbv = (const float*)d_in[25];
  const float* cbo = (const float*)d_in[26];
  const float* cnq_w = (const float*)d_in[27];
  const float* cnk_w = (const float*)d_in[28];
  const float* w1 = (const float*)d_in[29];
  const float* b1 = (const float*)d_in[30];
  const float* w2 = (const float*)d_in[31];
  const float* b2 = (const float*)d_in[32];

  int L  = in_sizes[0] / DMODEL;
  int LC = in_sizes[1] / DMODEL;
  int F  = in_sizes[2] / (6 * DMODEL);
  int FS = L / F;
  int FF = in_sizes[30];
  long long LD = (long long)L * DMODEL;
  float* outp = (float*)d_out;
  int N3 = 3 * DMODEL, N2 = 2 * DMODEL;

  // ---- workspace layout with liveness-based aliasing ----
  char* p = (char*)d_ws;
  auto alloc = [&](size_t bytes) -> char* {
    char* r = p; p += (bytes + 255) & ~(size_t)255; return r;
  };
  size_t DD = (size_t)DMODEL * DMODEL;
  bf16* wqkv_t = (bf16*)alloc(DD * 3 * 2);
  bf16* wto_t  = (bf16*)alloc(DD * 2);
  bf16* cwq_t  = (bf16*)alloc(DD * 2);
  bf16* cwkv_t = (bf16*)alloc(DD * 2 * 2);
  bf16* cwo_t  = (bf16*)alloc(DD * 2);
  bf16* w1t = (bf16*)alloc((size_t)DMODEL * FF * 2);
  bf16* w2t = (bf16*)alloc((size_t)DMODEL * FF * 2);
  float* bqkv = (float*)alloc((size_t)N3 * 4);
  float* cbkv = (float*)alloc((size_t)N2 * 4);
  float* hbuf = (float*)alloc((size_t)LD * 4);
  bf16* nh   = (bf16*)alloc((size_t)LD * 2);
  bf16* qb   = (bf16*)alloc((size_t)LD * 2);
  bf16* kb   = (bf16*)alloc((size_t)LD * 2);
  bf16* ab   = (bf16*)alloc((size_t)LD * 2);
  bf16* vtc  = (bf16*)alloc((size_t)LC * DMODEL * 2);
  bf16* encb = (bf16*)alloc((size_t)LC * DMODEL * 2);
  // BIG1: phase2 qkvb (L*N3 bf16) -> phase4 ckvb (LC*N2 bf16) -> phase5 ffb (L*FF bf16)
  char* BIG1 = alloc((size_t)L * FF * 2);
  bf16* qkvb = (bf16*)BIG1;
  bf16* ckvb = (bf16*)BIG1;
  bf16* ffb  = (bf16*)BIG1;
  // BIG2: phase2-3 vtb (LD bf16) -> phase3/4/5 split-K partials Pp (3 x LD fp32)
  char* BIG2 = alloc((size_t)LD * 3 * 4);
  bf16* vtb = (bf16*)BIG2;
  float* Pp = (float*)BIG2;
  (void)ws_size; (void)n_in; (void)out_size;

  dim3 gWdd(DMODEL / 32, DMODEL / 32);
  wt_kernel<<<gWdd, 256, 0, stream>>>(wq, wqkv_t, DMODEL, DMODEL);
  wt_kernel<<<gWdd, 256, 0, stream>>>(wk, wqkv_t + DD, DMODEL, DMODEL);
  wt_kernel<<<gWdd, 256, 0, stream>>>(wv, wqkv_t + 2 * DD, DMODEL, DMODEL);
  wt_kernel<<<gWdd, 256, 0, stream>>>(wo, wto_t, DMODEL, DMODEL);
  wt_kernel<<<gWdd, 256, 0, stream>>>(cwq, cwq_t, DMODEL, DMODEL);
  wt_kernel<<<gWdd, 256, 0, stream>>>(cwk, cwkv_t, DMODEL, DMODEL);
  wt_kernel<<<gWdd, 256, 0, stream>>>(cwv, cwkv_t + DD, DMODEL, DMODEL);
  wt_kernel<<<gWdd, 256, 0, stream>>>(cwo, cwo_t, DMODEL, DMODEL);
  wt_kernel<<<dim3(DMODEL / 32, FF / 32), 256, 0, stream>>>(w1, w1t, DMODEL, FF);
  wt_kernel<<<dim3(FF / 32, DMODEL / 32), 256, 0, stream>>>(w2, w2t, FF, DMODEL);
  catbias_kernel<<<6, 256, 0, stream>>>(bqkv, bq, bk, bv, cbkv, cbk, cbv);

  int gxC = (LC + 127) / 128;
  int gmx = (L + 255) / 256;      // 256-row tiles in L
  int nqb = (L + 63) / 64;        // 64-q flash blocks
  const float qs = 0.08838834764831845f;  // 1/sqrt(128)

  // 1) AdaLN-modulated LN of hidden
  ln_kernel<<<L, 256, 0, stream>>>(hs, nh, sst, temb, 0, 1, FS);
  // 2) fused q/k/v projection, bf16 out with fused bias
  gemm256<<<dim3(gmx * (N3 / 256), 1), 512, 0, stream>>>(nh, wqkv_t, bqkv, nullptr, qkvb,
                                                         L, N3, DMODEL, 0, 1, 0);
  rmsrope_qk_kernel<<<L, 256, 0, stream>>>(qkvb, N3, qb, kb, nq_w, nk_w, cosb, sinb, qs);
  transposev_kernel<<<dim3((L + 63) / 64, DMODEL / 64), 256, 0, stream>>>(qkvb, N3, 2 * DMODEL, vtb, L);
  // 3) self attention (block-causal)
  flash2_kernel<<<NHEADS * nqb, 256, 0, stream>>>(qb, kb, vtb, ab, L, L, FS, 1, nqb);
  gemm256<<<dim3(gmx * (DMODEL / 256), 3), 512, 0, stream>>>(ab, wto_t, nullptr, Pp, nullptr,
                                                             L, DMODEL, DMODEL, 0, 3, LD);
  modresid_ln_kernel<<<L, 256, 0, stream>>>(hs, Pp, 3, LD, bo, hbuf, sst, temb, 2, FS,
                                            ln2_g, ln2_b, nh);
  // 4) cross attention
  gemm256<<<dim3(gmx * (DMODEL / 256), 3), 512, 0, stream>>>(nh, cwq_t, nullptr, Pp, nullptr,
                                                             L, DMODEL, DMODEL, 0, 3, LD);
  rms_rope_kernel<<<L, 256, 0, stream>>>(Pp, 3, LD, nullptr, DMODEL, 0, cbq, qb, cnq_w, nullptr, nullptr, 0, qs);
  cast_kernel<<<(int)(((long long)LC * DMODEL + 255) / 256), 256, 0, stream>>>(enc, encb, (long long)LC * DMODEL);
  gemm_bt<<<dim3(gxC * (N2 / 128), 1), 256, 0, stream>>>(encb, cwkv_t, cbkv, nullptr, ckvb,
                                                         LC, N2, DMODEL, 0, DMODEL, 0);
  rms_rope_kernel<<<LC, 256, 0, stream>>>(nullptr, 0, 0, ckvb, N2, 0, nullptr, kb, cnk_w, nullptr, nullptr, 0, 1.0f);
  transposev_kernel<<<dim3((LC + 63) / 64, DMODEL / 64), 256, 0, stream>>>(ckvb, N2, DMODEL, vtc, LC);
  flash2_kernel<<<NHEADS * nqb, 256, 0, stream>>>(qb, kb, vtc, ab, L, LC, FS, 0, nqb);
  gemm256<<<dim3(gmx * (DMODEL / 256), 3), 512, 0, stream>>>(ab, cwo_t, nullptr, Pp, nullptr,
                                                             L, DMODEL, DMODEL, 0, 3, LD);
  addf_ln_kernel<<<L, 256, 0, stream>>>(hbuf, Pp, 3, LD, cbo, sst, temb, 3, 4, FS, nh);
  // 5) FFN
  gemm256<<<dim3(gmx * (FF / 256), 1), 512, 0, stream>>>(nh, w1t, b1, nullptr, ffb,
                                                         L, FF, DMODEL, 1, 1, 0);
  gemm256<<<dim3(gmx * (DMODEL / 256), 3), 512, 0, stream>>>(ffb, w2t, nullptr, Pp, nullptr,
                                                             L, DMODEL, FF, 0, 3, LD);
  modresid_kernel<<<(int)((LD + 255) / 256), 256, 0, stream>>>(hbuf, Pp, 3, LD, b2, outp, sst, temb, 5, FS, LD);
}

// Round 8
// 1069.120 us; speedup vs baseline: 1.1695x; 1.1695x over previous
//
#include <hip/hip_runtime.h>
#include <hip/hip_bf16.h>
#include <math.h>

typedef __bf16 bf16;
typedef __bf16 bf16x8 __attribute__((ext_vector_type(8)));
typedef float  f32x4  __attribute__((ext_vector_type(4)));
typedef unsigned int u32;

#define DMODEL 1536
#define NHEADS 12
#define HD 128
#define HDH 64

__device__ __forceinline__ void async16(const void* g, void* l) {
  __builtin_amdgcn_global_load_lds((const __attribute__((address_space(1))) u32*)g,
                                   (__attribute__((address_space(3))) u32*)l, 16, 0, 0);
}

// ---------------- block reduction (block = 256) ----------------
__device__ inline void block_reduce2(float& a, float& b) {
  __shared__ float sa[4], sb[4];
  #pragma unroll
  for (int off = 32; off; off >>= 1) {
    a += __shfl_xor(a, off);
    b += __shfl_xor(b, off);
  }
  int w = threadIdx.x >> 6;
  if ((threadIdx.x & 63) == 0) { sa[w] = a; sb[w] = b; }
  __syncthreads();
  a = sa[0] + sa[1] + sa[2] + sa[3];
  b = sb[0] + sb[1] + sb[2] + sb[3];
  __syncthreads();
}

// ---------------- LayerNorm (+AdaLN modulate), phase-1 only ----------------
__global__ __launch_bounds__(256)
void ln_kernel(const float* __restrict__ X, bf16* __restrict__ Y,
               const float* __restrict__ sst, const float* __restrict__ temb,
               int jshift, int jscale, int FS)
{
  int row = blockIdx.x;
  const float* x = X + (size_t)row * DMODEL;
  float v[6];
  float s1 = 0.f, s2 = 0.f;
  #pragma unroll
  for (int i = 0; i < 6; i++) {
    float t = x[threadIdx.x + i * 256];
    v[i] = t; s1 += t; s2 += t * t;
  }
  block_reduce2(s1, s2);
  float mean = s1 * (1.f / DMODEL);
  float var  = s2 * (1.f / DMODEL) - mean * mean;
  float rs = rsqrtf(var + 1e-6f);
  int f = row / FS;
  bf16* y = Y + (size_t)row * DMODEL;
  #pragma unroll
  for (int i = 0; i < 6; i++) {
    int d = threadIdx.x + i * 256;
    float t = (v[i] - mean) * rs;
    float sc = sst[jscale * DMODEL + d] + temb[(f * 6 + jscale) * DMODEL + d];
    float sh = sst[jshift * DMODEL + d] + temb[(f * 6 + jshift) * DMODEL + d];
    y[d] = (bf16)(t * (1.f + sc) + sh);
  }
}

// ---------------- RMSNorm (+ optional RoPE), dual-mode input ----------------
__global__ __launch_bounds__(256)
void rms_rope_kernel(const float* __restrict__ P, int S, long long MN,
                     const bf16* __restrict__ Xb, int RS, int CO,
                     const float* __restrict__ bias, bf16* __restrict__ Y,
                     const float* __restrict__ w,
                     const float* __restrict__ cosb, const float* __restrict__ sinb,
                     int dorope, float oscale)
{
  __shared__ float rowbuf[DMODEL];
  int row = blockIdx.x;
  float v[6];
  float s2 = 0.f, dummy = 0.f;
  if (Xb) {
    const bf16* x = Xb + (size_t)row * RS + CO;
    #pragma unroll
    for (int i = 0; i < 6; i++) {
      int d = threadIdx.x + i * 256;
      float t = (float)x[d];
      v[i] = t; rowbuf[d] = t; s2 += t * t;
    }
  } else {
    const float* x = P + (size_t)row * RS + CO;
    #pragma unroll
    for (int i = 0; i < 6; i++) {
      int d = threadIdx.x + i * 256;
      float t = bias[d];
      for (int s = 0; s < S; s++) t += x[(size_t)s * MN + d];
      v[i] = t; rowbuf[d] = t; s2 += t * t;
    }
  }
  __syncthreads();
  block_reduce2(s2, dummy);
  float rs = rsqrtf(s2 * (1.f / DMODEL) + 1e-6f) * oscale;
  bf16* y = Y + (size_t)row * DMODEL;
  if (dorope) {
    #pragma unroll
    for (int i = 0; i < 3; i++) {
      int p = threadIdx.x + i * 256;
      int d0 = 2 * p, d1 = 2 * p + 1;
      float y0 = rowbuf[d0] * rs * w[d0];
      float y1 = rowbuf[d1] * rs * w[d1];
      int ih = p & 63;
      float c = cosb[(size_t)row * HDH + ih];
      float s = sinb[(size_t)row * HDH + ih];
      y[d0] = (bf16)(y0 * c - y1 * s);
      y[d1] = (bf16)(y0 * s + y1 * c);
    }
  } else {
    #pragma unroll
    for (int i = 0; i < 6; i++) {
      int d = threadIdx.x + i * 256;
      y[d] = (bf16)(v[i] * rs * w[d]);
    }
  }
}

// ---------------- fused q+k RMSNorm+RoPE (one launch for both) ----------------
__global__ __launch_bounds__(256)
void rmsrope_qk_kernel(const bf16* __restrict__ Xb, int RS,
                       bf16* __restrict__ Q, bf16* __restrict__ Kb,
                       const float* __restrict__ wq, const float* __restrict__ wk,
                       const float* __restrict__ cosb, const float* __restrict__ sinb,
                       float qscale)
{
  __shared__ float rowbuf[DMODEL];
  int row = blockIdx.x;
  for (int pass = 0; pass < 2; ++pass) {
    const bf16* x = Xb + (size_t)row * RS + (pass ? DMODEL : 0);
    const float* wv = pass ? wk : wq;
    bf16* y = (pass ? Kb : Q) + (size_t)row * DMODEL;
    float osc = pass ? 1.0f : qscale;
    float s2 = 0.f, dmy = 0.f;
    #pragma unroll
    for (int i = 0; i < 6; i++) {
      int d = threadIdx.x + i * 256;
      float t = (float)x[d];
      rowbuf[d] = t; s2 += t * t;
    }
    __syncthreads();
    block_reduce2(s2, dmy);
    float rs = rsqrtf(s2 * (1.f / DMODEL) + 1e-6f) * osc;
    #pragma unroll
    for (int i = 0; i < 3; i++) {
      int p = threadIdx.x + i * 256;
      int d0 = 2 * p, d1 = 2 * p + 1;
      float y0 = rowbuf[d0] * rs * wv[d0];
      float y1 = rowbuf[d1] * rs * wv[d1];
      int ih = p & 63;
      float c = cosb[(size_t)row * HDH + ih];
      float s = sinb[(size_t)row * HDH + ih];
      y[d0] = (bf16)(y0 * c - y1 * s);
      y[d1] = (bf16)(y0 * s + y1 * c);
    }
    __syncthreads();
  }
}

// ---------------- weight transpose+cast: W (K,N) fp32 -> Wt (N,K) bf16 ----------------
__global__ __launch_bounds__(256)
void wt_kernel(const float* __restrict__ W, bf16* __restrict__ Wt, int K, int N)
{
  __shared__ float T[32][33];
  int k0 = blockIdx.x * 32, n0 = blockIdx.y * 32;
  int tx = threadIdx.x & 31, ty = threadIdx.x >> 5;
  #pragma unroll
  for (int i = 0; i < 4; i++)
    T[ty + 8 * i][tx] = W[(size_t)(k0 + ty + 8 * i) * N + n0 + tx];
  __syncthreads();
  #pragma unroll
  for (int i = 0; i < 4; i++)
    Wt[(size_t)(n0 + ty + 8 * i) * K + k0 + tx] = (bf16)T[tx][ty + 8 * i];
}

// ---------------- bias concat ----------------
__global__ __launch_bounds__(256)
void catbias_kernel(float* __restrict__ bqkv, const float* __restrict__ bq,
                    const float* __restrict__ bk, const float* __restrict__ bv,
                    float* __restrict__ cbkv, const float* __restrict__ cbk,
                    const float* __restrict__ cbv)
{
  int i = blockIdx.x * 256 + threadIdx.x;
  if (i < DMODEL) {
    bqkv[i] = bq[i]; bqkv[DMODEL + i] = bk[i]; bqkv[2 * DMODEL + i] = bv[i];
    cbkv[i] = cbk[i]; cbkv[DMODEL + i] = cbv[i];
  }
}

// ---------------- GEMM m97-style 128^2 (kept for small-grid ckv) ----------------
__global__ __launch_bounds__(256)
void gemm_bt(const bf16* __restrict__ A, const bf16* __restrict__ Bt,
             const float* __restrict__ bias, float* __restrict__ Cf,
             bf16* __restrict__ Cb, int M, int N, int K, int act,
             int Ks, long long MN)
{
  __shared__ bf16 As[128 * 32];
  __shared__ bf16 Bs[128 * 32];
  int tid = threadIdx.x, lane = tid & 63, w = tid >> 6;
  int wm = w >> 1, wn = w & 1;
  int l16 = lane & 15, quad = lane >> 4;

  int gx = (M + 127) >> 7, gy = N >> 7;
  int per_panel = gx << 3;
  int bid = blockIdx.x;
  int panel = bid / per_panel;
  int rem = bid - panel * per_panel;
  int pc0 = panel << 3;
  int ncols = gy - pc0; if (ncols > 8) ncols = 8;
  int by = pc0 + rem % ncols;
  int bx = rem / ncols;
  int bm = bx * 128, bn = by * 128;

  int kb0 = blockIdx.y * Ks;

  int rl = lane >> 2;
  int kk = (lane & 3) * 8;
  int r0 = (2 * w) * 16 + rl, r1 = (2 * w + 1) * 16 + rl;
  int am0 = bm + r0; if (am0 > M - 1) am0 = M - 1;
  int am1 = bm + r1; if (am1 > M - 1) am1 = M - 1;
  const bf16* a0 = A + (size_t)am0 * K + kk;
  const bf16* a1 = A + (size_t)am1 * K + kk;
  const bf16* b0 = Bt + (size_t)(bn + r0) * K + kk;
  const bf16* b1 = Bt + (size_t)(bn + r1) * K + kk;
  bf16* lA0 = As + (2 * w) * 512; bf16* lA1 = As + (2 * w + 1) * 512;
  bf16* lB0 = Bs + (2 * w) * 512; bf16* lB1 = Bs + (2 * w + 1) * 512;

  f32x4 acc[4][4] = {};
  int kend = kb0 + Ks;
  for (int k0 = kb0; k0 < kend; k0 += 32) {
    async16(a0 + k0, lA0);
    async16(a1 + k0, lA1);
    async16(b0 + k0, lB0);
    async16(b1 + k0, lB1);
    __syncthreads();
    bf16x8 af[4], bfv[4];
    #pragma unroll
    for (int mi = 0; mi < 4; mi++)
      af[mi] = *(const bf16x8*)&As[(wm * 64 + mi * 16 + l16) * 32 + quad * 8];
    #pragma unroll
    for (int ni = 0; ni < 4; ni++)
      bfv[ni] = *(const bf16x8*)&Bs[(wn * 64 + ni * 16 + l16) * 32 + quad * 8];
    #pragma unroll
    for (int mi = 0; mi < 4; mi++)
      #pragma unroll
      for (int ni = 0; ni < 4; ni++)
        acc[mi][ni] = __builtin_amdgcn_mfma_f32_16x16x32_bf16(af[mi], bfv[ni], acc[mi][ni], 0, 0, 0);
    __syncthreads();
  }
  float* Cfo = Cf ? Cf + (size_t)blockIdx.y * MN : nullptr;
  #pragma unroll
  for (int mi = 0; mi < 4; mi++) {
    #pragma unroll
    for (int r = 0; r < 4; r++) {
      int m = bm + wm * 64 + mi * 16 + quad * 4 + r;
      if (m < M) {
        #pragma unroll
        for (int ni = 0; ni < 4; ni++) {
          int n = bn + wn * 64 + ni * 16 + l16;
          float val = acc[mi][ni][r] + (bias ? bias[n] : 0.f);
          if (act == 1) {
            float u = val + 0.044715f * val * val * val;
            float z = 1.5957691216057308f * u;
            val = val / (1.f + __expf(-z));
          }
          if (Cfo) Cfo[(size_t)m * N + n] = val;
          else     Cb[(size_t)m * N + n] = (bf16)val;
        }
      }
    }
  }
}

// ---------------- GEMM 256^2, BK=32, 4-deep circular buffer (R4-best) ----------
__global__ __launch_bounds__(512, 2)
void gemm256(const bf16* __restrict__ A, const bf16* __restrict__ Bt,
             const float* __restrict__ bias, float* __restrict__ Cf,
             bf16* __restrict__ Cb, int M, int N, int K, int act,
             int S, long long MN)
{
  __shared__ bf16 LDS[4][2][16 * 512];  // [buf][0=A,1=B][8192 bf16 = 16KB]
  int tid = threadIdx.x, lane = tid & 63, w = tid >> 6;
  int wm = w >> 2, wn = w & 3;
  int l16 = lane & 15, quad = lane >> 4;

  int gmx = (M + 255) >> 8, gny = N >> 8;
  int per_panel = gmx << 3;
  int bid = blockIdx.x;
  int panel = bid / per_panel;
  int rem = bid - panel * per_panel;
  int pc0 = panel << 3;
  int ncols = gny - pc0; if (ncols > 8) ncols = 8;
  int by = pc0 + rem % ncols;
  int bx = rem / ncols;
  int bm = bx << 8, bn = by << 8;

  int NTtot = K >> 5;
  int sidx = blockIdx.y;
  int basek = NTtot / S, remk = NTtot % S;
  int NT = basek + (sidx < remk ? 1 : 0);
  int t0k = sidx * basek + (sidx < remk ? sidx : remk);
  int kb0 = t0k << 5;

  int aro = (l16 * 64 + quad * 16) ^ ((l16 >> 3) << 5);
  char* ldsb = (char*)&LDS[0][0][0];   // buffer stride 32768B; B at +16384

  int srl = lane >> 2;
  int sc16 = (lane & 3) ^ (((lane >> 5) & 1) << 1);
  int Mm1 = M - 1, Nm1 = N - 1;
  int ga0 = bm + w * 16 + srl;        if (ga0 > Mm1) ga0 = Mm1;
  int ga1 = bm + 128 + w * 16 + srl;  if (ga1 > Mm1) ga1 = Mm1;
  int gb0 = bn + w * 16 + srl;        if (gb0 > Nm1) gb0 = Nm1;
  int gb1 = bn + 128 + w * 16 + srl;  if (gb1 > Nm1) gb1 = Nm1;
  const bf16* Ag0 = A + (size_t)ga0 * K + kb0 + sc16 * 8;
  const bf16* Ag1 = A + (size_t)ga1 * K + kb0 + sc16 * 8;
  const bf16* Bg0 = Bt + (size_t)gb0 * K + kb0 + sc16 * 8;
  const bf16* Bg1 = Bt + (size_t)gb1 * K + kb0 + sc16 * 8;

#define STG(tt) do { int _k = (tt) * 32; char* _d = ldsb + ((tt) & 3) * 32768 + w * 1024; \
    async16(Ag0 + _k, _d);          async16(Ag1 + _k, _d + 8192); \
    async16(Bg0 + _k, _d + 16384);  async16(Bg1 + _k, _d + 24576); } while (0)
#define MFMA_(d, a, b) d = __builtin_amdgcn_mfma_f32_16x16x32_bf16(a, b, d, 0, 0, 0)

  STG(0);
  if (NT > 1) STG(1);
  if (NT > 2) STG(2);
  if (NT > 2)      { asm volatile("s_waitcnt vmcnt(8)" ::: "memory"); }
  else if (NT > 1) { asm volatile("s_waitcnt vmcnt(4)" ::: "memory"); }
  else             { asm volatile("s_waitcnt vmcnt(0)" ::: "memory"); }
  __builtin_amdgcn_s_barrier();

  f32x4 acc[8][4] = {};
  for (int t = 0; t < NT; ++t) {
    if (t + 3 < NT) STG(t + 3);
    const char* Ar = ldsb + (t & 3) * 32768 + wm * 8192 + aro;
    const char* Br = ldsb + (t & 3) * 32768 + 16384 + wn * 4096 + aro;
    bf16x8 a[8], bv[4];
    #pragma unroll
    for (int i = 0; i < 4; i++) bv[i] = *(const bf16x8*)(Br + i * 1024);
    #pragma unroll
    for (int i = 0; i < 8; i++) a[i] = *(const bf16x8*)(Ar + i * 1024);
    #pragma unroll
    for (int mi = 0; mi < 8; mi++)
      #pragma unroll
      for (int ni = 0; ni < 4; ni++)
        MFMA_(acc[mi][ni], a[mi], bv[ni]);
    int remt = NT - 1 - t;
    if (remt >= 3)      { asm volatile("s_waitcnt vmcnt(8)" ::: "memory"); __builtin_amdgcn_s_barrier(); }
    else if (remt == 2) { asm volatile("s_waitcnt vmcnt(4)" ::: "memory"); __builtin_amdgcn_s_barrier(); }
    else if (remt == 1) { asm volatile("s_waitcnt vmcnt(0)" ::: "memory"); __builtin_amdgcn_s_barrier(); }
  }
#undef STG
#undef MFMA_

  float* Cfo = Cf ? Cf + (size_t)blockIdx.y * MN : nullptr;
  #pragma unroll
  for (int mi = 0; mi < 8; mi++) {
    #pragma unroll
    for (int r = 0; r < 4; r++) {
      int m = bm + wm * 128 + mi * 16 + quad * 4 + r;
      if (m < M) {
        #pragma unroll
        for (int ni = 0; ni < 4; ni++) {
          int n = bn + wn * 64 + ni * 16 + l16;
          float val = acc[mi][ni][r] + (bias ? bias[n] : 0.f);
          if (act == 1) {
            float u = val + 0.044715f * val * val * val;
            float z = 1.5957691216057308f * u;
            val = val / (1.f + __expf(-z));
          }
          if (Cfo) Cfo[(size_t)m * N + n] = val;
          else     Cb[(size_t)m * N + n] = (bf16)val;
        }
      }
    }
  }
}

// ---------------- V transpose from bf16 source (bias pre-applied) ----------------
__global__ __launch_bounds__(256)
void transposev_kernel(const bf16* __restrict__ Xb, int RS, int CO,
                       bf16* __restrict__ Vt, int L)
{
  __shared__ bf16 T[64][65];
  int l0 = blockIdx.x * 64, n0 = blockIdx.y * 64;
  int tid = threadIdx.x;
  int r = tid >> 2;
  int c8 = (tid & 3) * 16;
  int lc = l0 + r; if (lc > L - 1) lc = L - 1;
  const bf16* src = Xb + (size_t)lc * RS + CO + n0 + c8;
  #pragma unroll
  for (int i = 0; i < 16; i++) T[r][c8 + i] = src[i];
  __syncthreads();
  #pragma unroll
  for (int i = 0; i < 16; i++) {
    int l = l0 + c8 + i;
    if (l < L) Vt[(size_t)(n0 + r) * L + l] = T[c8 + i][r];
  }
}

// ---------------- flash attention v2: 64-q blocks, 4 waves (R0-R5 best) ----------
__global__ __launch_bounds__(256)
void flash2_kernel(const bf16* __restrict__ Q, const bf16* __restrict__ Kg,
                   const bf16* __restrict__ Vt, bf16* __restrict__ O,
                   int Lq, int Lk, int FS, int causal, int nqb)
{
  __shared__ bf16 Kt[64 * 128];
  __shared__ bf16 Vtile[128 * 64];
  __shared__ bf16 Pl[4][16][72];
  int tid = threadIdx.x, lane = tid & 63, w = tid >> 6;
  int l16 = lane & 15, quad = lane >> 4;
  int bid = blockIdx.x;
  int h = bid % NHEADS;
  int qb = nqb - 1 - (bid / NHEADS);
  int q0b = qb * 64;
  int q0w = q0b + w * 16;

  int qrow = q0w + l16; if (qrow > Lq - 1) qrow = Lq - 1;
  const bf16* qbase = Q + (size_t)qrow * DMODEL + h * HD + quad * 8;
  bf16x8 qf[4];
  #pragma unroll
  for (int dc = 0; dc < 4; dc++) qf[dc] = *(const bf16x8*)(qbase + dc * 32);

  int kvrow[4];
  int kvmin_w = Lk, kv_end = Lk;
  if (causal) {
    #pragma unroll
    for (int r = 0; r < 4; r++) {
      int qr = q0w + quad * 4 + r; if (qr > Lq - 1) qr = Lq - 1;
      kvrow[r] = (qr / FS + 1) * FS;
    }
    int q0c = q0w; if (q0c > Lq - 1) q0c = Lq - 1;
    kvmin_w = (q0c / FS + 1) * FS;
    int qlast = q0b + 63; if (qlast > Lq - 1) qlast = Lq - 1;
    kv_end = (qlast / FS + 1) * FS;
    if (kv_end > Lk) kv_end = Lk;
  }

  f32x4 acc_o[8] = {};
  float m_i[4], l_i[4];
  #pragma unroll
  for (int r = 0; r < 4; r++) { m_i[r] = -1e30f; l_i[r] = 0.f; }

  for (int kb = 0; kb < kv_end; kb += 64) {
    #pragma unroll
    for (int j = 0; j < 4; j++) {
      int u = w * 256 + j * 64 + lane;
      int row = u >> 4;
      int c = (u & 15) ^ (row & 15);
      int krow = kb + row; if (krow > Lk - 1) krow = Lk - 1;
      async16(Kg + (size_t)krow * DMODEL + h * HD + c * 8,
              Kt + (size_t)(w * 256 + j * 64) * 8);
    }
    #pragma unroll
    for (int j = 0; j < 4; j++) {
      int u = w * 256 + j * 64 + lane;
      int row = u >> 3;
      int c = (u & 7) ^ (row & 7);
      async16(Vt + (size_t)(h * HD + row) * Lk + kb + c * 8,
              Vtile + (size_t)(w * 256 + j * 64) * 8);
    }
    __syncthreads();

    f32x4 s[4] = {};
    #pragma unroll
    for (int nk = 0; nk < 4; nk++) {
      #pragma unroll
      for (int dc = 0; dc < 4; dc++) {
        bf16x8 kf = *(const bf16x8*)&Kt[(((nk * 16 + l16) << 4) + ((4 * dc + quad) ^ l16)) * 8];
        s[nk] = __builtin_amdgcn_mfma_f32_16x16x32_bf16(qf[dc], kf, s[nk], 0, 0, 0);
      }
    }

    bool need_mask = causal && (kb + 64 > kvmin_w);
    float p[4][4];
    #pragma unroll
    for (int r = 0; r < 4; r++) {
      #pragma unroll
      for (int nk = 0; nk < 4; nk++) {
        float sv = s[nk][r];
        if (need_mask && (kb + nk * 16 + l16 >= kvrow[r])) sv = -1e30f;
        p[nk][r] = sv;
      }
      float bm = fmaxf(fmaxf(p[0][r], p[1][r]), fmaxf(p[2][r], p[3][r]));
      #pragma unroll
      for (int off = 8; off; off >>= 1) bm = fmaxf(bm, __shfl_xor(bm, off));
      float mn = fmaxf(m_i[r], bm);
      float alpha = __expf(m_i[r] - mn);
      m_i[r] = mn;
      float ps = 0.f;
      #pragma unroll
      for (int nk = 0; nk < 4; nk++) {
        float e = __expf(p[nk][r] - mn);
        p[nk][r] = e; ps += e;
      }
      #pragma unroll
      for (int off = 8; off; off >>= 1) ps += __shfl_xor(ps, off);
      l_i[r] = l_i[r] * alpha + ps;
      #pragma unroll
      for (int t = 0; t < 8; t++) acc_o[t][r] *= alpha;
    }

    #pragma unroll
    for (int nk = 0; nk < 4; nk++)
      #pragma unroll
      for (int r = 0; r < 4; r++)
        Pl[w][quad * 4 + r][nk * 16 + l16] = (bf16)p[nk][r];
    __threadfence_block();
    bf16x8 pf0 = *(const bf16x8*)&Pl[w][l16][quad * 8];
    bf16x8 pf1 = *(const bf16x8*)&Pl[w][l16][32 + quad * 8];

    #pragma unroll
    for (int t = 0; t < 8; t++) {
      bf16x8 vf0 = *(const bf16x8*)&Vtile[(((t * 16 + l16) << 3) + ((quad) ^ (l16 & 7))) * 8];
      bf16x8 vf1 = *(const bf16x8*)&Vtile[(((t * 16 + l16) << 3) + ((4 + quad) ^ (l16 & 7))) * 8];
      acc_o[t] = __builtin_amdgcn_mfma_f32_16x16x32_bf16(pf0, vf0, acc_o[t], 0, 0, 0);
      acc_o[t] = __builtin_amdgcn_mfma_f32_16x16x32_bf16(pf1, vf1, acc_o[t], 0, 0, 0);
    }
    __syncthreads();
  }

  #pragma unroll
  for (int r = 0; r < 4; r++) {
    int m = q0w + quad * 4 + r;
    if (m < Lq) {
      float inv = 1.f / l_i[r];
      bf16* obase = O + (size_t)m * DMODEL + h * HD;
      #pragma unroll
      for (int t = 0; t < 8; t++)
        obase[t * 16 + l16] = (bf16)(acc_o[t][r] * inv);
    }
  }
}

// ---------------- fused: split-K reduce + gated residual + affine LN ----------------
__global__ __launch_bounds__(256)
void modresid_ln_kernel(const float* __restrict__ base, const float* __restrict__ P,
                        int S, long long MN, const float* __restrict__ bias,
                        float* __restrict__ hout,
                        const float* __restrict__ sst, const float* __restrict__ temb,
                        int jg, int FS,
                        const float* __restrict__ g2, const float* __restrict__ b2,
                        bf16* __restrict__ nh)
{
  int row = blockIdx.x;
  int f = row / FS;
  float v[6]; float s1 = 0.f, s2 = 0.f;
  #pragma unroll
  for (int i = 0; i < 6; i++) {
    int d = threadIdx.x + i * 256;
    long long idx = (size_t)row * DMODEL + d;
    float gg = sst[jg * DMODEL + d] + temb[(f * 6 + jg) * DMODEL + d];
    float t = bias[d];
    for (int s = 0; s < S; s++) t += P[(size_t)s * MN + idx];
    float hv = base[idx] + t * gg;
    hout[idx] = hv;
    v[i] = hv; s1 += hv; s2 += hv * hv;
  }
  block_reduce2(s1, s2);
  float mean = s1 * (1.f / DMODEL);
  float var  = s2 * (1.f / DMODEL) - mean * mean;
  float rs = rsqrtf(var + 1e-6f);
  bf16* y = nh + (size_t)row * DMODEL;
  #pragma unroll
  for (int i = 0; i < 6; i++) {
    int d = threadIdx.x + i * 256;
    y[d] = (bf16)((v[i] - mean) * rs * g2[d] + b2[d]);
  }
}

// ---------------- fused: split-K reduce + residual + AdaLN-mod LN ----------------
__global__ __launch_bounds__(256)
void addf_ln_kernel(float* __restrict__ hbuf, const float* __restrict__ P,
                    int S, long long MN, const float* __restrict__ bias,
                    const float* __restrict__ sst, const float* __restrict__ temb,
                    int jshift, int jscale, int FS, bf16* __restrict__ nh)
{
  int row = blockIdx.x;
  int f = row / FS;
  float v[6]; float s1 = 0.f, s2 = 0.f;
  #pragma unroll
  for (int i = 0; i < 6; i++) {
    int d = threadIdx.x + i * 256;
    long long idx = (size_t)row * DMODEL + d;
    float t = bias[d];
    for (int s = 0; s < S; s++) t += P[(size_t)s * MN + idx];
    float hv = hbuf[idx] + t;
    hbuf[idx] = hv;
    v[i] = hv; s1 += hv; s2 += hv * hv;
  }
  block_reduce2(s1, s2);
  float mean = s1 * (1.f / DMODEL);
  float var  = s2 * (1.f / DMODEL) - mean * mean;
  float rs = rsqrtf(var + 1e-6f);
  bf16* y = nh + (size_t)row * DMODEL;
  #pragma unroll
  for (int i = 0; i < 6; i++) {
    int d = threadIdx.x + i * 256;
    float t = (v[i] - mean) * rs;
    float sc = sst[jscale * DMODEL + d] + temb[(f * 6 + jscale) * DMODEL + d];
    float sh = sst[jshift * DMODEL + d] + temb[(f * 6 + jshift) * DMODEL + d];
    y[d] = (bf16)(t * (1.f + sc) + sh);
  }
}

// ---------------- elementwise (final split-K reduce + gated residual) ----------------
__global__ __launch_bounds__(256)
void modresid_kernel(const float* __restrict__ base, const float* __restrict__ P,
                     int S, long long MN, const float* __restrict__ bias,
                     float* __restrict__ out,
                     const float* __restrict__ sst, const float* __restrict__ temb,
                     int jg, int FS, long long total)
{
  long long i = (long long)blockIdx.x * 256 + threadIdx.x;
  if (i >= total) return;
  int d = (int)(i % DMODEL);
  int f = (int)((i / DMODEL) / FS);
  float g = sst[jg * DMODEL + d] + temb[(f * 6 + jg) * DMODEL + d];
  float v = bias[d];
  for (int s = 0; s < S; s++) v += P[(size_t)s * MN + i];
  out[i] = base[i] + v * g;
}

__global__ __launch_bounds__(256)
void cast_kernel(const float* __restrict__ x, bf16* __restrict__ y, long long total)
{
  long long i = (long long)blockIdx.x * 256 + threadIdx.x;
  if (i < total) y[i] = (bf16)x[i];
}

// ---------------- orchestration ----------------
extern "C" void kernel_launch(void* const* d_in, const int* in_sizes, int n_in,
                              void* d_out, int out_size, void* d_ws, size_t ws_size,
                              hipStream_t stream)
{
  const float* hs   = (const float*)d_in[0];
  const float* enc  = (const float*)d_in[1];
  const float* temb = (const float*)d_in[2];
  const float* cosb = (const float*)d_in[3];
  const float* sinb = (const float*)d_in[4];
  const float* sst  = (const float*)d_in[6];
  const float* wq = (const float*)d_in[7];
  const float* wk = (const float*)d_in[8];
  const float* wv = (const float*)d_in[9];
  const float* wo = (const float*)d_in[10];
  const float* bq = (const float*)d_in[11];
  const float* bk = (const float*)d_in[12];
  const float* bv = (const float*)d_in[13];
  const float* bo = (const float*)d_in[14];
  const float* nq_w = (const float*)d_in[15];
  const float* nk_w = (const float*)d_in[16];
  const float* ln2_g = (const float*)d_in[17];
  const float* ln2_b = (const float*)d_in[18];
  const float* cwq = (const float*)d_in[19];
  const float* cwk = (const float*)d_in[20];
  const float* cwv = (const float*)d_in[21];
  const float* cwo = (const float*)d_in[22];
  const float* cbq = (const float*)d_in[23];
  const float* cbk = (const float*)d_in[24];
  const float* cbv = (const float*)d_in[25];
  const float* cbo = (const float*)d_in[26];
  const float* cnq_w = (const float*)d_in[27];
  const float* cnk_w = (const float*)d_in[28];
  const float* w1 = (const float*)d_in[29];
  const float* b1 = (const float*)d_in[30];
  const float* w2 = (const float*)d_in[31];
  const float* b2 = (const float*)d_in[32];

  int L  = in_sizes[0] / DMODEL;
  int LC = in_sizes[1] / DMODEL;
  int F  = in_sizes[2] / (6 * DMODEL);
  int FS = L / F;
  int FF = in_sizes[30];
  long long LD = (long long)L * DMODEL;
  float* outp = (float*)d_out;
  int N3 = 3 * DMODEL, N2 = 2 * DMODEL;

  // ---- workspace layout with liveness-based aliasing ----
  char* p = (char*)d_ws;
  auto alloc = [&](size_t bytes) -> char* {
    char* r = p; p += (bytes + 255) & ~(size_t)255; return r;
  };
  size_t DD = (size_t)DMODEL * DMODEL;
  bf16* wqkv_t = (bf16*)alloc(DD * 3 * 2);
  bf16* wto_t  = (bf16*)alloc(DD * 2);
  bf16* cwq_t  = (bf16*)alloc(DD * 2);
  bf16* cwkv_t = (bf16*)alloc(DD * 2 * 2);
  bf16* cwo_t  = (bf16*)alloc(DD * 2);
  bf16* w1t = (bf16*)alloc((size_t)DMODEL * FF * 2);
  bf16* w2t = (bf16*)alloc((size_t)DMODEL * FF * 2);
  float* bqkv = (float*)alloc((size_t)N3 * 4);
  float* cbkv = (float*)alloc((size_t)N2 * 4);
  float* hbuf = (float*)alloc((size_t)LD * 4);
  bf16* nh   = (bf16*)alloc((size_t)LD * 2);
  bf16* qb   = (bf16*)alloc((size_t)LD * 2);
  bf16* kb   = (bf16*)alloc((size_t)LD * 2);
  bf16* ab   = (bf16*)alloc((size_t)LD * 2);
  bf16* vtc  = (bf16*)alloc((size_t)LC * DMODEL * 2);
  bf16* encb = (bf16*)alloc((size_t)LC * DMODEL * 2);
  // BIG1: phase2 qkvb (L*N3 bf16) -> phase4 ckvb (LC*N2 bf16) -> phase5 ffb (L*FF bf16)
  char* BIG1 = alloc((size_t)L * FF * 2);
  bf16* qkvb = (bf16*)BIG1;
  bf16* ckvb = (bf16*)BIG1;
  bf16* ffb  = (bf16*)BIG1;
  // BIG2: phase2-3 vtb (LD bf16) -> phase3/4/5 split-K partials Pp (3 x LD fp32)
  char* BIG2 = alloc((size_t)LD * 3 * 4);
  bf16* vtb = (bf16*)BIG2;
  float* Pp = (float*)BIG2;
  (void)ws_size; (void)n_in; (void)out_size;

  dim3 gWdd(DMODEL / 32, DMODEL / 32);
  wt_kernel<<<gWdd, 256, 0, stream>>>(wq, wqkv_t, DMODEL, DMODEL);
  wt_kernel<<<gWdd, 256, 0, stream>>>(wk, wqkv_t + DD, DMODEL, DMODEL);
  wt_kernel<<<gWdd, 256, 0, stream>>>(wv, wqkv_t + 2 * DD, DMODEL, DMODEL);
  wt_kernel<<<gWdd, 256, 0, stream>>>(wo, wto_t, DMODEL, DMODEL);
  wt_kernel<<<gWdd, 256, 0, stream>>>(cwq, cwq_t, DMODEL, DMODEL);
  wt_kernel<<<gWdd, 256, 0, stream>>>(cwk, cwkv_t, DMODEL, DMODEL);
  wt_kernel<<<gWdd, 256, 0, stream>>>(cwv, cwkv_t + DD, DMODEL, DMODEL);
  wt_kernel<<<gWdd, 256, 0, stream>>>(cwo, cwo_t, DMODEL, DMODEL);
  wt_kernel<<<dim3(DMODEL / 32, FF / 32), 256, 0, stream>>>(w1, w1t, DMODEL, FF);
  wt_kernel<<<dim3(FF / 32, DMODEL / 32), 256, 0, stream>>>(w2, w2t, FF, DMODEL);
  catbias_kernel<<<6, 256, 0, stream>>>(bqkv, bq, bk, bv, cbkv, cbk, cbv);

  int gxC = (LC + 127) / 128;
  int gmx = (L + 255) / 256;      // 256-row tiles in L
  int nqb = (L + 63) / 64;        // 64-q flash blocks
  const float qs = 0.08838834764831845f;  // 1/sqrt(128)

  // 1) AdaLN-modulated LN of hidden
  ln_kernel<<<L, 256, 0, stream>>>(hs, nh, sst, temb, 0, 1, FS);
  // 2) fused q/k/v projection, bf16 out with fused bias
  gemm256<<<dim3(gmx * (N3 / 256), 1), 512, 0, stream>>>(nh, wqkv_t, bqkv, nullptr, qkvb,
                                                         L, N3, DMODEL, 0, 1, 0);
  rmsrope_qk_kernel<<<L, 256, 0, stream>>>(qkvb, N3, qb, kb, nq_w, nk_w, cosb, sinb, qs);
  transposev_kernel<<<dim3((L + 63) / 64, DMODEL / 64), 256, 0, stream>>>(qkvb, N3, 2 * DMODEL, vtb, L);
  // 3) self attention (block-causal)
  flash2_kernel<<<NHEADS * nqb, 256, 0, stream>>>(qb, kb, vtb, ab, L, L, FS, 1, nqb);
  gemm256<<<dim3(gmx * (DMODEL / 256), 3), 512, 0, stream>>>(ab, wto_t, nullptr, Pp, nullptr,
                                                             L, DMODEL, DMODEL, 0, 3, LD);
  modresid_ln_kernel<<<L, 256, 0, stream>>>(hs, Pp, 3, LD, bo, hbuf, sst, temb, 2, FS,
                                            ln2_g, ln2_b, nh);
  // 4) cross attention
  gemm256<<<dim3(gmx * (DMODEL / 256), 3), 512, 0, stream>>>(nh, cwq_t, nullptr, Pp, nullptr,
                                                             L, DMODEL, DMODEL, 0, 3, LD);
  rms_rope_kernel<<<L, 256, 0, stream>>>(Pp, 3, LD, nullptr, DMODEL, 0, cbq, qb, cnq_w, nullptr, nullptr, 0, qs);
  cast_kernel<<<(int)(((long long)LC * DMODEL + 255) / 256), 256, 0, stream>>>(enc, encb, (long long)LC * DMODEL);
  gemm_bt<<<dim3(gxC * (N2 / 128), 1), 256, 0, stream>>>(encb, cwkv_t, cbkv, nullptr, ckvb,
                                                         LC, N2, DMODEL, 0, DMODEL, 0);
  rms_rope_kernel<<<LC, 256, 0, stream>>>(nullptr, 0, 0, ckvb, N2, 0, nullptr, kb, cnk_w, nullptr, nullptr, 0, 1.0f);
  transposev_kernel<<<dim3((LC + 63) / 64, DMODEL / 64), 256, 0, stream>>>(ckvb, N2, DMODEL, vtc, LC);
  flash2_kernel<<<NHEADS * nqb, 256, 0, stream>>>(qb, kb, vtc, ab, L, LC, FS, 0, nqb);
  gemm256<<<dim3(gmx * (DMODEL / 256), 3), 512, 0, stream>>>(ab, cwo_t, nullptr, Pp, nullptr,
                                                             L, DMODEL, DMODEL, 0, 3, LD);
  addf_ln_kernel<<<L, 256, 0, stream>>>(hbuf, Pp, 3, LD, cbo, sst, temb, 3, 4, FS, nh);
  // 5) FFN
  gemm256<<<dim3(gmx * (FF / 256), 1), 512, 0, stream>>>(nh, w1t, b1, nullptr, ffb,
                                                         L, FF, DMODEL, 1, 1, 0);
  gemm256<<<dim3(gmx * (DMODEL / 256), 3), 512, 0, stream>>>(ffb, w2t, nullptr, Pp, nullptr,
                                                             L, DMODEL, FF, 0, 3, LD);
  modresid_kernel<<<(int)((LD + 255) / 256), 256, 0, stream>>>(hbuf, Pp, 3, LD, b2, outp, sst, temb, 5, FS, LD);
}

// Round 9
// 1024.029 us; speedup vs baseline: 1.2210x; 1.0440x over previous
//
#include <hip/hip_runtime.h>
#include <hip/hip_bf16.h>
#include <math.h>

typedef __bf16 bf16;
typedef __bf16 bf16x8 __attribute__((ext_vector_type(8)));
typedef float  f32x4  __attribute__((ext_vector_type(4)));
typedef unsigned int u32;

#define DMODEL 1536
#define NHEADS 12
#define HD 128
#define HDH 64

__device__ __forceinline__ void async16(const void* g, void* l) {
  __builtin_amdgcn_global_load_lds((const __attribute__((address_space(1))) u32*)g,
                                   (__attribute__((address_space(3))) u32*)l, 16, 0, 0);
}

// ---------------- block reduction (block = 256) ----------------
__device__ inline void block_reduce2(float& a, float& b) {
  __shared__ float sa[4], sb[4];
  #pragma unroll
  for (int off = 32; off; off >>= 1) {
    a += __shfl_xor(a, off);
    b += __shfl_xor(b, off);
  }
  int w = threadIdx.x >> 6;
  if ((threadIdx.x & 63) == 0) { sa[w] = a; sb[w] = b; }
  __syncthreads();
  a = sa[0] + sa[1] + sa[2] + sa[3];
  b = sb[0] + sb[1] + sb[2] + sb[3];
  __syncthreads();
}

// ---------------- LayerNorm (+AdaLN modulate), phase-1 only ----------------
__global__ __launch_bounds__(256)
void ln_kernel(const float* __restrict__ X, bf16* __restrict__ Y,
               const float* __restrict__ sst, const float* __restrict__ temb,
               int jshift, int jscale, int FS)
{
  int row = blockIdx.x;
  const float* x = X + (size_t)row * DMODEL;
  float v[6];
  float s1 = 0.f, s2 = 0.f;
  #pragma unroll
  for (int i = 0; i < 6; i++) {
    float t = x[threadIdx.x + i * 256];
    v[i] = t; s1 += t; s2 += t * t;
  }
  block_reduce2(s1, s2);
  float mean = s1 * (1.f / DMODEL);
  float var  = s2 * (1.f / DMODEL) - mean * mean;
  float rs = rsqrtf(var + 1e-6f);
  int f = row / FS;
  bf16* y = Y + (size_t)row * DMODEL;
  #pragma unroll
  for (int i = 0; i < 6; i++) {
    int d = threadIdx.x + i * 256;
    float t = (v[i] - mean) * rs;
    float sc = sst[jscale * DMODEL + d] + temb[(f * 6 + jscale) * DMODEL + d];
    float sh = sst[jshift * DMODEL + d] + temb[(f * 6 + jshift) * DMODEL + d];
    y[d] = (bf16)(t * (1.f + sc) + sh);
  }
}

// ---------------- RMSNorm (+ optional RoPE), dual-mode input ----------------
__global__ __launch_bounds__(256)
void rms_rope_kernel(const float* __restrict__ P, int S, long long MN,
                     const bf16* __restrict__ Xb, int RS, int CO,
                     const float* __restrict__ bias, bf16* __restrict__ Y,
                     const float* __restrict__ w,
                     const float* __restrict__ cosb, const float* __restrict__ sinb,
                     int dorope, float oscale)
{
  __shared__ float rowbuf[DMODEL];
  int row = blockIdx.x;
  float v[6];
  float s2 = 0.f, dummy = 0.f;
  if (Xb) {
    const bf16* x = Xb + (size_t)row * RS + CO;
    #pragma unroll
    for (int i = 0; i < 6; i++) {
      int d = threadIdx.x + i * 256;
      float t = (float)x[d];
      v[i] = t; rowbuf[d] = t; s2 += t * t;
    }
  } else {
    const float* x = P + (size_t)row * RS + CO;
    #pragma unroll
    for (int i = 0; i < 6; i++) {
      int d = threadIdx.x + i * 256;
      float t = bias[d];
      for (int s = 0; s < S; s++) t += x[(size_t)s * MN + d];
      v[i] = t; rowbuf[d] = t; s2 += t * t;
    }
  }
  __syncthreads();
  block_reduce2(s2, dummy);
  float rs = rsqrtf(s2 * (1.f / DMODEL) + 1e-6f) * oscale;
  bf16* y = Y + (size_t)row * DMODEL;
  if (dorope) {
    #pragma unroll
    for (int i = 0; i < 3; i++) {
      int p = threadIdx.x + i * 256;
      int d0 = 2 * p, d1 = 2 * p + 1;
      float y0 = rowbuf[d0] * rs * w[d0];
      float y1 = rowbuf[d1] * rs * w[d1];
      int ih = p & 63;
      float c = cosb[(size_t)row * HDH + ih];
      float s = sinb[(size_t)row * HDH + ih];
      y[d0] = (bf16)(y0 * c - y1 * s);
      y[d1] = (bf16)(y0 * s + y1 * c);
    }
  } else {
    #pragma unroll
    for (int i = 0; i < 6; i++) {
      int d = threadIdx.x + i * 256;
      y[d] = (bf16)(v[i] * rs * w[d]);
    }
  }
}

// ---------------- fused q+k RMSNorm+RoPE (one launch for both) ----------------
__global__ __launch_bounds__(256)
void rmsrope_qk_kernel(const bf16* __restrict__ Xb, int RS,
                       bf16* __restrict__ Q, bf16* __restrict__ Kb,
                       const float* __restrict__ wq, const float* __restrict__ wk,
                       const float* __restrict__ cosb, const float* __restrict__ sinb,
                       float qscale)
{
  __shared__ float rowbuf[DMODEL];
  int row = blockIdx.x;
  for (int pass = 0; pass < 2; ++pass) {
    const bf16* x = Xb + (size_t)row * RS + (pass ? DMODEL : 0);
    const float* wv = pass ? wk : wq;
    bf16* y = (pass ? Kb : Q) + (size_t)row * DMODEL;
    float osc = pass ? 1.0f : qscale;
    float s2 = 0.f, dmy = 0.f;
    #pragma unroll
    for (int i = 0; i < 6; i++) {
      int d = threadIdx.x + i * 256;
      float t = (float)x[d];
      rowbuf[d] = t; s2 += t * t;
    }
    __syncthreads();
    block_reduce2(s2, dmy);
    float rs = rsqrtf(s2 * (1.f / DMODEL) + 1e-6f) * osc;
    #pragma unroll
    for (int i = 0; i < 3; i++) {
      int p = threadIdx.x + i * 256;
      int d0 = 2 * p, d1 = 2 * p + 1;
      float y0 = rowbuf[d0] * rs * wv[d0];
      float y1 = rowbuf[d1] * rs * wv[d1];
      int ih = p & 63;
      float c = cosb[(size_t)row * HDH + ih];
      float s = sinb[(size_t)row * HDH + ih];
      y[d0] = (bf16)(y0 * c - y1 * s);
      y[d1] = (bf16)(y0 * s + y1 * c);
    }
    __syncthreads();
  }
}

// ---------------- weight transpose+cast: W (K,N) fp32 -> Wt (N,K) bf16 ----------------
__global__ __launch_bounds__(256)
void wt_kernel(const float* __restrict__ W, bf16* __restrict__ Wt, int K, int N)
{
  __shared__ float T[32][33];
  int k0 = blockIdx.x * 32, n0 = blockIdx.y * 32;
  int tx = threadIdx.x & 31, ty = threadIdx.x >> 5;
  #pragma unroll
  for (int i = 0; i < 4; i++)
    T[ty + 8 * i][tx] = W[(size_t)(k0 + ty + 8 * i) * N + n0 + tx];
  __syncthreads();
  #pragma unroll
  for (int i = 0; i < 4; i++)
    Wt[(size_t)(n0 + ty + 8 * i) * K + k0 + tx] = (bf16)T[tx][ty + 8 * i];
}

// ---------------- batched 8x (DMODEL x DMODEL) transpose+cast, one launch ------
// dst is 8 contiguous DD-bf16 matrices: [wq,wk,wv,wo,cwq,cwk,cwv,cwo]
__global__ __launch_bounds__(256)
void wt8_kernel(const float* __restrict__ w0, const float* __restrict__ w1,
                const float* __restrict__ w2, const float* __restrict__ w3,
                const float* __restrict__ w4, const float* __restrict__ w5,
                const float* __restrict__ w6, const float* __restrict__ w7,
                bf16* __restrict__ dst)
{
  const float* srcs[8] = {w0, w1, w2, w3, w4, w5, w6, w7};
  const float* W = srcs[blockIdx.z];
  bf16* Wt = dst + (size_t)blockIdx.z * DMODEL * DMODEL;
  __shared__ float T[32][33];
  int k0 = blockIdx.x * 32, n0 = blockIdx.y * 32;
  int tx = threadIdx.x & 31, ty = threadIdx.x >> 5;
  #pragma unroll
  for (int i = 0; i < 4; i++)
    T[ty + 8 * i][tx] = W[(size_t)(k0 + ty + 8 * i) * DMODEL + n0 + tx];
  __syncthreads();
  #pragma unroll
  for (int i = 0; i < 4; i++)
    Wt[(size_t)(n0 + ty + 8 * i) * DMODEL + k0 + tx] = (bf16)T[tx][ty + 8 * i];
}

// ---------------- bias concat ----------------
__global__ __launch_bounds__(256)
void catbias_kernel(float* __restrict__ bqkv, const float* __restrict__ bq,
                    const float* __restrict__ bk, const float* __restrict__ bv,
                    float* __restrict__ cbkv, const float* __restrict__ cbk,
                    const float* __restrict__ cbv)
{
  int i = blockIdx.x * 256 + threadIdx.x;
  if (i < DMODEL) {
    bqkv[i] = bq[i]; bqkv[DMODEL + i] = bk[i]; bqkv[2 * DMODEL + i] = bv[i];
    cbkv[i] = cbk[i]; cbkv[DMODEL + i] = cbv[i];
  }
}

// ---------------- GEMM m97-style 128^2 (kept for small-grid ckv) ----------------
__global__ __launch_bounds__(256)
void gemm_bt(const bf16* __restrict__ A, const bf16* __restrict__ Bt,
             const float* __restrict__ bias, float* __restrict__ Cf,
             bf16* __restrict__ Cb, int M, int N, int K, int act,
             int Ks, long long MN)
{
  __shared__ bf16 As[128 * 32];
  __shared__ bf16 Bs[128 * 32];
  int tid = threadIdx.x, lane = tid & 63, w = tid >> 6;
  int wm = w >> 1, wn = w & 1;
  int l16 = lane & 15, quad = lane >> 4;

  int gx = (M + 127) >> 7, gy = N >> 7;
  int per_panel = gx << 3;
  int bid = blockIdx.x;
  int panel = bid / per_panel;
  int rem = bid - panel * per_panel;
  int pc0 = panel << 3;
  int ncols = gy - pc0; if (ncols > 8) ncols = 8;
  int by = pc0 + rem % ncols;
  int bx = rem / ncols;
  int bm = bx * 128, bn = by * 128;

  int kb0 = blockIdx.y * Ks;

  int rl = lane >> 2;
  int kk = (lane & 3) * 8;
  int r0 = (2 * w) * 16 + rl, r1 = (2 * w + 1) * 16 + rl;
  int am0 = bm + r0; if (am0 > M - 1) am0 = M - 1;
  int am1 = bm + r1; if (am1 > M - 1) am1 = M - 1;
  const bf16* a0 = A + (size_t)am0 * K + kk;
  const bf16* a1 = A + (size_t)am1 * K + kk;
  const bf16* b0 = Bt + (size_t)(bn + r0) * K + kk;
  const bf16* b1 = Bt + (size_t)(bn + r1) * K + kk;
  bf16* lA0 = As + (2 * w) * 512; bf16* lA1 = As + (2 * w + 1) * 512;
  bf16* lB0 = Bs + (2 * w) * 512; bf16* lB1 = Bs + (2 * w + 1) * 512;

  f32x4 acc[4][4] = {};
  int kend = kb0 + Ks;
  for (int k0 = kb0; k0 < kend; k0 += 32) {
    async16(a0 + k0, lA0);
    async16(a1 + k0, lA1);
    async16(b0 + k0, lB0);
    async16(b1 + k0, lB1);
    __syncthreads();
    bf16x8 af[4], bfv[4];
    #pragma unroll
    for (int mi = 0; mi < 4; mi++)
      af[mi] = *(const bf16x8*)&As[(wm * 64 + mi * 16 + l16) * 32 + quad * 8];
    #pragma unroll
    for (int ni = 0; ni < 4; ni++)
      bfv[ni] = *(const bf16x8*)&Bs[(wn * 64 + ni * 16 + l16) * 32 + quad * 8];
    #pragma unroll
    for (int mi = 0; mi < 4; mi++)
      #pragma unroll
      for (int ni = 0; ni < 4; ni++)
        acc[mi][ni] = __builtin_amdgcn_mfma_f32_16x16x32_bf16(af[mi], bfv[ni], acc[mi][ni], 0, 0, 0);
    __syncthreads();
  }
  float* Cfo = Cf ? Cf + (size_t)blockIdx.y * MN : nullptr;
  #pragma unroll
  for (int mi = 0; mi < 4; mi++) {
    #pragma unroll
    for (int r = 0; r < 4; r++) {
      int m = bm + wm * 64 + mi * 16 + quad * 4 + r;
      if (m < M) {
        #pragma unroll
        for (int ni = 0; ni < 4; ni++) {
          int n = bn + wn * 64 + ni * 16 + l16;
          float val = acc[mi][ni][r] + (bias ? bias[n] : 0.f);
          if (act == 1) {
            float u = val + 0.044715f * val * val * val;
            float z = 1.5957691216057308f * u;
            val = val / (1.f + __expf(-z));
          }
          if (Cfo) Cfo[(size_t)m * N + n] = val;
          else     Cb[(size_t)m * N + n] = (bf16)val;
        }
      }
    }
  }
}

// ---------------- GEMM 256^2, BK=32, 4-deep circular buffer (R4-best) ----------
__global__ __launch_bounds__(512, 2)
void gemm256(const bf16* __restrict__ A, const bf16* __restrict__ Bt,
             const float* __restrict__ bias, float* __restrict__ Cf,
             bf16* __restrict__ Cb, int M, int N, int K, int act,
             int S, long long MN)
{
  __shared__ bf16 LDS[4][2][16 * 512];  // [buf][0=A,1=B][8192 bf16 = 16KB]
  int tid = threadIdx.x, lane = tid & 63, w = tid >> 6;
  int wm = w >> 2, wn = w & 3;
  int l16 = lane & 15, quad = lane >> 4;

  int gmx = (M + 255) >> 8, gny = N >> 8;
  int per_panel = gmx << 3;
  int bid = blockIdx.x;
  int panel = bid / per_panel;
  int rem = bid - panel * per_panel;
  int pc0 = panel << 3;
  int ncols = gny - pc0; if (ncols > 8) ncols = 8;
  int by = pc0 + rem % ncols;
  int bx = rem / ncols;
  int bm = bx << 8, bn = by << 8;

  int NTtot = K >> 5;
  int sidx = blockIdx.y;
  int basek = NTtot / S, remk = NTtot % S;
  int NT = basek + (sidx < remk ? 1 : 0);
  int t0k = sidx * basek + (sidx < remk ? sidx : remk);
  int kb0 = t0k << 5;

  int aro = (l16 * 64 + quad * 16) ^ ((l16 >> 3) << 5);
  char* ldsb = (char*)&LDS[0][0][0];   // buffer stride 32768B; B at +16384

  int srl = lane >> 2;
  int sc16 = (lane & 3) ^ (((lane >> 5) & 1) << 1);
  int Mm1 = M - 1, Nm1 = N - 1;
  int ga0 = bm + w * 16 + srl;        if (ga0 > Mm1) ga0 = Mm1;
  int ga1 = bm + 128 + w * 16 + srl;  if (ga1 > Mm1) ga1 = Mm1;
  int gb0 = bn + w * 16 + srl;        if (gb0 > Nm1) gb0 = Nm1;
  int gb1 = bn + 128 + w * 16 + srl;  if (gb1 > Nm1) gb1 = Nm1;
  const bf16* Ag0 = A + (size_t)ga0 * K + kb0 + sc16 * 8;
  const bf16* Ag1 = A + (size_t)ga1 * K + kb0 + sc16 * 8;
  const bf16* Bg0 = Bt + (size_t)gb0 * K + kb0 + sc16 * 8;
  const bf16* Bg1 = Bt + (size_t)gb1 * K + kb0 + sc16 * 8;

#define STG(tt) do { int _k = (tt) * 32; char* _d = ldsb + ((tt) & 3) * 32768 + w * 1024; \
    async16(Ag0 + _k, _d);          async16(Ag1 + _k, _d + 8192); \
    async16(Bg0 + _k, _d + 16384);  async16(Bg1 + _k, _d + 24576); } while (0)
#define MFMA_(d, a, b) d = __builtin_amdgcn_mfma_f32_16x16x32_bf16(a, b, d, 0, 0, 0)

  STG(0);
  if (NT > 1) STG(1);
  if (NT > 2) STG(2);
  if (NT > 2)      { asm volatile("s_waitcnt vmcnt(8)" ::: "memory"); }
  else if (NT > 1) { asm volatile("s_waitcnt vmcnt(4)" ::: "memory"); }
  else             { asm volatile("s_waitcnt vmcnt(0)" ::: "memory"); }
  __builtin_amdgcn_s_barrier();

  f32x4 acc[8][4] = {};
  for (int t = 0; t < NT; ++t) {
    if (t + 3 < NT) STG(t + 3);
    const char* Ar = ldsb + (t & 3) * 32768 + wm * 8192 + aro;
    const char* Br = ldsb + (t & 3) * 32768 + 16384 + wn * 4096 + aro;
    bf16x8 a[8], bv[4];
    #pragma unroll
    for (int i = 0; i < 4; i++) bv[i] = *(const bf16x8*)(Br + i * 1024);
    #pragma unroll
    for (int i = 0; i < 8; i++) a[i] = *(const bf16x8*)(Ar + i * 1024);
    #pragma unroll
    for (int mi = 0; mi < 8; mi++)
      #pragma unroll
      for (int ni = 0; ni < 4; ni++)
        MFMA_(acc[mi][ni], a[mi], bv[ni]);
    int remt = NT - 1 - t;
    if (remt >= 3)      { asm volatile("s_waitcnt vmcnt(8)" ::: "memory"); __builtin_amdgcn_s_barrier(); }
    else if (remt == 2) { asm volatile("s_waitcnt vmcnt(4)" ::: "memory"); __builtin_amdgcn_s_barrier(); }
    else if (remt == 1) { asm volatile("s_waitcnt vmcnt(0)" ::: "memory"); __builtin_amdgcn_s_barrier(); }
  }
#undef STG
#undef MFMA_

  float* Cfo = Cf ? Cf + (size_t)blockIdx.y * MN : nullptr;
  #pragma unroll
  for (int mi = 0; mi < 8; mi++) {
    #pragma unroll
    for (int r = 0; r < 4; r++) {
      int m = bm + wm * 128 + mi * 16 + quad * 4 + r;
      if (m < M) {
        #pragma unroll
        for (int ni = 0; ni < 4; ni++) {
          int n = bn + wn * 64 + ni * 16 + l16;
          float val = acc[mi][ni][r] + (bias ? bias[n] : 0.f);
          if (act == 1) {
            float u = val + 0.044715f * val * val * val;
            float z = 1.5957691216057308f * u;
            val = val / (1.f + __expf(-z));
          }
          if (Cfo) Cfo[(size_t)m * N + n] = val;
          else     Cb[(size_t)m * N + n] = (bf16)val;
        }
      }
    }
  }
}

// ---------------- V transpose from bf16 source (bias pre-applied) ----------------
__global__ __launch_bounds__(256)
void transposev_kernel(const bf16* __restrict__ Xb, int RS, int CO,
                       bf16* __restrict__ Vt, int L)
{
  __shared__ bf16 T[64][65];
  int l0 = blockIdx.x * 64, n0 = blockIdx.y * 64;
  int tid = threadIdx.x;
  int r = tid >> 2;
  int c8 = (tid & 3) * 16;
  int lc = l0 + r; if (lc > L - 1) lc = L - 1;
  const bf16* src = Xb + (size_t)lc * RS + CO + n0 + c8;
  #pragma unroll
  for (int i = 0; i < 16; i++) T[r][c8 + i] = src[i];
  __syncthreads();
  #pragma unroll
  for (int i = 0; i < 16; i++) {
    int l = l0 + c8 + i;
    if (l < L) Vt[(size_t)(n0 + r) * L + l] = T[c8 + i][r];
  }
}

// ---------------- flash attention: 64-q blocks, 4 waves, fixed-ref softmax ------
// q rows are RMS-normed * 1/sqrt(128) -> ||q||=1; ||k||=sqrt(128) (unit norm-w),
// so |s| <= sqrt(128) ~ 11.3 by Cauchy-Schwarz: exp(s) <= e^11.3 fits f32/bf16.
// => no running max, no rescale (masked s=-1e30 -> exp=0).
__global__ __launch_bounds__(256)
void flash2_kernel(const bf16* __restrict__ Q, const bf16* __restrict__ Kg,
                   const bf16* __restrict__ Vt, bf16* __restrict__ O,
                   int Lq, int Lk, int FS, int causal, int nqb)
{
  __shared__ bf16 Kt[64 * 128];
  __shared__ bf16 Vtile[128 * 64];
  __shared__ bf16 Pl[4][16][72];
  int tid = threadIdx.x, lane = tid & 63, w = tid >> 6;
  int l16 = lane & 15, quad = lane >> 4;
  int bid = blockIdx.x;
  int h = bid % NHEADS;
  int qb = nqb - 1 - (bid / NHEADS);
  int q0b = qb * 64;
  int q0w = q0b + w * 16;

  int qrow = q0w + l16; if (qrow > Lq - 1) qrow = Lq - 1;
  const bf16* qbase = Q + (size_t)qrow * DMODEL + h * HD + quad * 8;
  bf16x8 qf[4];
  #pragma unroll
  for (int dc = 0; dc < 4; dc++) qf[dc] = *(const bf16x8*)(qbase + dc * 32);

  int kvrow[4];
  int kvmin_w = Lk, kv_end = Lk;
  if (causal) {
    #pragma unroll
    for (int r = 0; r < 4; r++) {
      int qr = q0w + quad * 4 + r; if (qr > Lq - 1) qr = Lq - 1;
      kvrow[r] = (qr / FS + 1) * FS;
    }
    int q0c = q0w; if (q0c > Lq - 1) q0c = Lq - 1;
    kvmin_w = (q0c / FS + 1) * FS;
    int qlast = q0b + 63; if (qlast > Lq - 1) qlast = Lq - 1;
    kv_end = (qlast / FS + 1) * FS;
    if (kv_end > Lk) kv_end = Lk;
  }

  f32x4 acc_o[8] = {};
  float l_i[4];
  #pragma unroll
  for (int r = 0; r < 4; r++) l_i[r] = 0.f;

  for (int kb = 0; kb < kv_end; kb += 64) {
    #pragma unroll
    for (int j = 0; j < 4; j++) {
      int u = w * 256 + j * 64 + lane;
      int row = u >> 4;
      int c = (u & 15) ^ (row & 15);
      int krow = kb + row; if (krow > Lk - 1) krow = Lk - 1;
      async16(Kg + (size_t)krow * DMODEL + h * HD + c * 8,
              Kt + (size_t)(w * 256 + j * 64) * 8);
    }
    #pragma unroll
    for (int j = 0; j < 4; j++) {
      int u = w * 256 + j * 64 + lane;
      int row = u >> 3;
      int c = (u & 7) ^ (row & 7);
      async16(Vt + (size_t)(h * HD + row) * Lk + kb + c * 8,
              Vtile + (size_t)(w * 256 + j * 64) * 8);
    }
    __syncthreads();

    f32x4 s[4] = {};
    #pragma unroll
    for (int nk = 0; nk < 4; nk++) {
      #pragma unroll
      for (int dc = 0; dc < 4; dc++) {
        bf16x8 kf = *(const bf16x8*)&Kt[(((nk * 16 + l16) << 4) + ((4 * dc + quad) ^ l16)) * 8];
        s[nk] = __builtin_amdgcn_mfma_f32_16x16x32_bf16(qf[dc], kf, s[nk], 0, 0, 0);
      }
    }

    bool need_mask = causal && (kb + 64 > kvmin_w);
    float p[4][4];
    #pragma unroll
    for (int r = 0; r < 4; r++) {
      float ps = 0.f;
      #pragma unroll
      for (int nk = 0; nk < 4; nk++) {
        float sv = s[nk][r];
        if (need_mask && (kb + nk * 16 + l16 >= kvrow[r])) sv = -1e30f;
        float e = __expf(sv);
        p[nk][r] = e; ps += e;
      }
      #pragma unroll
      for (int off = 8; off; off >>= 1) ps += __shfl_xor(ps, off);
      l_i[r] += ps;
    }

    #pragma unroll
    for (int nk = 0; nk < 4; nk++)
      #pragma unroll
      for (int r = 0; r < 4; r++)
        Pl[w][quad * 4 + r][nk * 16 + l16] = (bf16)p[nk][r];
    __threadfence_block();
    bf16x8 pf0 = *(const bf16x8*)&Pl[w][l16][quad * 8];
    bf16x8 pf1 = *(const bf16x8*)&Pl[w][l16][32 + quad * 8];

    #pragma unroll
    for (int t = 0; t < 8; t++) {
      bf16x8 vf0 = *(const bf16x8*)&Vtile[(((t * 16 + l16) << 3) + ((quad) ^ (l16 & 7))) * 8];
      bf16x8 vf1 = *(const bf16x8*)&Vtile[(((t * 16 + l16) << 3) + ((4 + quad) ^ (l16 & 7))) * 8];
      acc_o[t] = __builtin_amdgcn_mfma_f32_16x16x32_bf16(pf0, vf0, acc_o[t], 0, 0, 0);
      acc_o[t] = __builtin_amdgcn_mfma_f32_16x16x32_bf16(pf1, vf1, acc_o[t], 0, 0, 0);
    }
    __syncthreads();
  }

  #pragma unroll
  for (int r = 0; r < 4; r++) {
    int m = q0w + quad * 4 + r;
    if (m < Lq) {
      float inv = 1.f / l_i[r];
      bf16* obase = O + (size_t)m * DMODEL + h * HD;
      #pragma unroll
      for (int t = 0; t < 8; t++)
        obase[t * 16 + l16] = (bf16)(acc_o[t][r] * inv);
    }
  }
}

// ---------------- fused: split-K reduce + gated residual + affine LN ----------------
__global__ __launch_bounds__(256)
void modresid_ln_kernel(const float* __restrict__ base, const float* __restrict__ P,
                        int S, long long MN, const float* __restrict__ bias,
                        float* __restrict__ hout,
                        const float* __restrict__ sst, const float* __restrict__ temb,
                        int jg, int FS,
                        const float* __restrict__ g2, const float* __restrict__ b2,
                        bf16* __restrict__ nh)
{
  int row = blockIdx.x;
  int f = row / FS;
  float v[6]; float s1 = 0.f, s2 = 0.f;
  #pragma unroll
  for (int i = 0; i < 6; i++) {
    int d = threadIdx.x + i * 256;
    long long idx = (size_t)row * DMODEL + d;
    float gg = sst[jg * DMODEL + d] + temb[(f * 6 + jg) * DMODEL + d];
    float t = bias[d];
    for (int s = 0; s < S; s++) t += P[(size_t)s * MN + idx];
    float hv = base[idx] + t * gg;
    hout[idx] = hv;
    v[i] = hv; s1 += hv; s2 += hv * hv;
  }
  block_reduce2(s1, s2);
  float mean = s1 * (1.f / DMODEL);
  float var  = s2 * (1.f / DMODEL) - mean * mean;
  float rs = rsqrtf(var + 1e-6f);
  bf16* y = nh + (size_t)row * DMODEL;
  #pragma unroll
  for (int i = 0; i < 6; i++) {
    int d = threadIdx.x + i * 256;
    y[d] = (bf16)((v[i] - mean) * rs * g2[d] + b2[d]);
  }
}

// ---------------- fused: split-K reduce + residual + AdaLN-mod LN ----------------
__global__ __launch_bounds__(256)
void addf_ln_kernel(float* __restrict__ hbuf, const float* __restrict__ P,
                    int S, long long MN, const float* __restrict__ bias,
                    const float* __restrict__ sst, const float* __restrict__ temb,
                    int jshift, int jscale, int FS, bf16* __restrict__ nh)
{
  int row = blockIdx.x;
  int f = row / FS;
  float v[6]; float s1 = 0.f, s2 = 0.f;
  #pragma unroll
  for (int i = 0; i < 6; i++) {
    int d = threadIdx.x + i * 256;
    long long idx = (size_t)row * DMODEL + d;
    float t = bias[d];
    for (int s = 0; s < S; s++) t += P[(size_t)s * MN + idx];
    float hv = hbuf[idx] + t;
    hbuf[idx] = hv;
    v[i] = hv; s1 += hv; s2 += hv * hv;
  }
  block_reduce2(s1, s2);
  float mean = s1 * (1.f / DMODEL);
  float var  = s2 * (1.f / DMODEL) - mean * mean;
  float rs = rsqrtf(var + 1e-6f);
  bf16* y = nh + (size_t)row * DMODEL;
  #pragma unroll
  for (int i = 0; i < 6; i++) {
    int d = threadIdx.x + i * 256;
    float t = (v[i] - mean) * rs;
    float sc = sst[jscale * DMODEL + d] + temb[(f * 6 + jscale) * DMODEL + d];
    float sh = sst[jshift * DMODEL + d] + temb[(f * 6 + jshift) * DMODEL + d];
    y[d] = (bf16)(t * (1.f + sc) + sh);
  }
}

// ---------------- elementwise (final split-K reduce + gated residual) ----------------
__global__ __launch_bounds__(256)
void modresid_kernel(const float* __restrict__ base, const float* __restrict__ P,
                     int S, long long MN, const float* __restrict__ bias,
                     float* __restrict__ out,
                     const float* __restrict__ sst, const float* __restrict__ temb,
                     int jg, int FS, long long total)
{
  long long i = (long long)blockIdx.x * 256 + threadIdx.x;
  if (i >= total) return;
  int d = (int)(i % DMODEL);
  int f = (int)((i / DMODEL) / FS);
  float g = sst[jg * DMODEL + d] + temb[(f * 6 + jg) * DMODEL + d];
  float v = bias[d];
  for (int s = 0; s < S; s++) v += P[(size_t)s * MN + i];
  out[i] = base[i] + v * g;
}

__global__ __launch_bounds__(256)
void cast_kernel(const float* __restrict__ x, bf16* __restrict__ y, long long total)
{
  long long i = (long long)blockIdx.x * 256 + threadIdx.x;
  if (i < total) y[i] = (bf16)x[i];
}

// ---------------- orchestration ----------------
extern "C" void kernel_launch(void* const* d_in, const int* in_sizes, int n_in,
                              void* d_out, int out_size, void* d_ws, size_t ws_size,
                              hipStream_t stream)
{
  const float* hs   = (const float*)d_in[0];
  const float* enc  = (const float*)d_in[1];
  const float* temb = (const float*)d_in[2];
  const float* cosb = (const float*)d_in[3];
  const float* sinb = (const float*)d_in[4];
  const float* sst  = (const float*)d_in[6];
  const float* wq = (const float*)d_in[7];
  const float* wk = (const float*)d_in[8];
  const float* wv = (const float*)d_in[9];
  const float* wo = (const float*)d_in[10];
  const float* bq = (const float*)d_in[11];
  const float* bk = (const float*)d_in[12];
  const float* bv = (const float*)d_in[13];
  const float* bo = (const float*)d_in[14];
  const float* nq_w = (const float*)d_in[15];
  const float* nk_w = (const float*)d_in[16];
  const float* ln2_g = (const float*)d_in[17];
  const float* ln2_b = (const float*)d_in[18];
  const float* cwq = (const float*)d_in[19];
  const float* cwk = (const float*)d_in[20];
  const float* cwv = (const float*)d_in[21];
  const float* cwo = (const float*)d_in[22];
  const float* cbq = (const float*)d_in[23];
  const float* cbk = (const float*)d_in[24];
  const float* cbv = (const float*)d_in[25];
  const float* cbo = (const float*)d_in[26];
  const float* cnq_w = (const float*)d_in[27];
  const float* cnk_w = (const float*)d_in[28];
  const float* w1 = (const float*)d_in[29];
  const float* b1 = (const float*)d_in[30];
  const float* w2 = (const float*)d_in[31];
  const float* b2 = (const float*)d_in[32];

  int L  = in_sizes[0] / DMODEL;
  int LC = in_sizes[1] / DMODEL;
  int F  = in_sizes[2] / (6 * DMODEL);
  int FS = L / F;
  int FF = in_sizes[30];
  long long LD = (long long)L * DMODEL;
  float* outp = (float*)d_out;
  int N3 = 3 * DMODEL, N2 = 2 * DMODEL;

  // ---- workspace layout with liveness-based aliasing ----
  char* p = (char*)d_ws;
  auto alloc = [&](size_t bytes) -> char* {
    char* r = p; p += (bytes + 255) & ~(size_t)255; return r;
  };
  size_t DD = (size_t)DMODEL * DMODEL;
  bf16* wqkv_t = (bf16*)alloc(DD * 3 * 2);   // wq,wk,wv   (contiguous with next 5)
  bf16* wto_t  = (bf16*)alloc(DD * 2);       // wo
  bf16* cwq_t  = (bf16*)alloc(DD * 2);       // cwq
  bf16* cwkv_t = (bf16*)alloc(DD * 2 * 2);   // cwk,cwv
  bf16* cwo_t  = (bf16*)alloc(DD * 2);       // cwo
  bf16* w1t = (bf16*)alloc((size_t)DMODEL * FF * 2);
  bf16* w2t = (bf16*)alloc((size_t)DMODEL * FF * 2);
  float* bqkv = (float*)alloc((size_t)N3 * 4);
  float* cbkv = (float*)alloc((size_t)N2 * 4);
  float* hbuf = (float*)alloc((size_t)LD * 4);
  bf16* nh   = (bf16*)alloc((size_t)LD * 2);
  bf16* qb   = (bf16*)alloc((size_t)LD * 2);
  bf16* kb   = (bf16*)alloc((size_t)LD * 2);
  bf16* ab   = (bf16*)alloc((size_t)LD * 2);
  bf16* vtc  = (bf16*)alloc((size_t)LC * DMODEL * 2);
  bf16* encb = (bf16*)alloc((size_t)LC * DMODEL * 2);
  // BIG1: phase2 qkvb (L*N3 bf16) -> phase4 ckvb (LC*N2 bf16) -> phase5 ffb (L*FF bf16)
  char* BIG1 = alloc((size_t)L * FF * 2);
  bf16* qkvb = (bf16*)BIG1;
  bf16* ckvb = (bf16*)BIG1;
  bf16* ffb  = (bf16*)BIG1;
  // BIG2: phase2-3 vtb (LD bf16) -> phase3/4/5 split-K partials Pp (3 x LD fp32)
  char* BIG2 = alloc((size_t)LD * 3 * 4);
  bf16* vtb = (bf16*)BIG2;
  float* Pp = (float*)BIG2;
  (void)ws_size; (void)n_in; (void)out_size;

  // 8 DxD transposes in ONE launch (dst region is contiguous: wq..cwo)
  wt8_kernel<<<dim3(DMODEL / 32, DMODEL / 32, 8), 256, 0, stream>>>(
      wq, wk, wv, wo, cwq, cwk, cwv, cwo, wqkv_t);
  wt_kernel<<<dim3(DMODEL / 32, FF / 32), 256, 0, stream>>>(w1, w1t, DMODEL, FF);
  wt_kernel<<<dim3(FF / 32, DMODEL / 32), 256, 0, stream>>>(w2, w2t, FF, DMODEL);
  catbias_kernel<<<6, 256, 0, stream>>>(bqkv, bq, bk, bv, cbkv, cbk, cbv);

  int gxC = (LC + 127) / 128;
  int gmx = (L + 255) / 256;      // 256-row tiles in L
  int nqb = (L + 63) / 64;        // 64-q flash blocks
  const float qs = 0.08838834764831845f;  // 1/sqrt(128)

  // 1) AdaLN-modulated LN of hidden
  ln_kernel<<<L, 256, 0, stream>>>(hs, nh, sst, temb, 0, 1, FS);
  // 2) fused q/k/v projection, bf16 out with fused bias
  gemm256<<<dim3(gmx * (N3 / 256), 1), 512, 0, stream>>>(nh, wqkv_t, bqkv, nullptr, qkvb,
                                                         L, N3, DMODEL, 0, 1, 0);
  rmsrope_qk_kernel<<<L, 256, 0, stream>>>(qkvb, N3, qb, kb, nq_w, nk_w, cosb, sinb, qs);
  transposev_kernel<<<dim3((L + 63) / 64, DMODEL / 64), 256, 0, stream>>>(qkvb, N3, 2 * DMODEL, vtb, L);
  // 3) self attention (block-causal)
  flash2_kernel<<<NHEADS * nqb, 256, 0, stream>>>(qb, kb, vtb, ab, L, L, FS, 1, nqb);
  gemm256<<<dim3(gmx * (DMODEL / 256), 3), 512, 0, stream>>>(ab, wto_t, nullptr, Pp, nullptr,
                                                             L, DMODEL, DMODEL, 0, 3, LD);
  modresid_ln_kernel<<<L, 256, 0, stream>>>(hs, Pp, 3, LD, bo, hbuf, sst, temb, 2, FS,
                                            ln2_g, ln2_b, nh);
  // 4) cross attention
  gemm256<<<dim3(gmx * (DMODEL / 256), 3), 512, 0, stream>>>(nh, cwq_t, nullptr, Pp, nullptr,
                                                             L, DMODEL, DMODEL, 0, 3, LD);
  rms_rope_kernel<<<L, 256, 0, stream>>>(Pp, 3, LD, nullptr, DMODEL, 0, cbq, qb, cnq_w, nullptr, nullptr, 0, qs);
  cast_kernel<<<(int)(((long long)LC * DMODEL + 255) / 256), 256, 0, stream>>>(enc, encb, (long long)LC * DMODEL);
  gemm_bt<<<dim3(gxC * (N2 / 128), 1), 256, 0, stream>>>(encb, cwkv_t, cbkv, nullptr, ckvb,
                                                         LC, N2, DMODEL, 0, DMODEL, 0);
  rms_rope_kernel<<<LC, 256, 0, stream>>>(nullptr, 0, 0, ckvb, N2, 0, nullptr, kb, cnk_w, nullptr, nullptr, 0, 1.0f);
  transposev_kernel<<<dim3((LC + 63) / 64, DMODEL / 64), 256, 0, stream>>>(ckvb, N2, DMODEL, vtc, LC);
  flash2_kernel<<<NHEADS * nqb, 256, 0, stream>>>(qb, kb, vtc, ab, L, LC, FS, 0, nqb);
  gemm256<<<dim3(gmx * (DMODEL / 256), 3), 512, 0, stream>>>(ab, cwo_t, nullptr, Pp, nullptr,
                                                             L, DMODEL, DMODEL, 0, 3, LD);
  addf_ln_kernel<<<L, 256, 0, stream>>>(hbuf, Pp, 3, LD, cbo, sst, temb, 3, 4, FS, nh);
  // 5) FFN
  gemm256<<<dim3(gmx * (FF / 256), 1), 512, 0, stream>>>(nh, w1t, b1, nullptr, ffb,
                                                         L, FF, DMODEL, 1, 1, 0);
  gemm256<<<dim3(gmx * (DMODEL / 256), 3), 512, 0, stream>>>(ffb, w2t, nullptr, Pp, nullptr,
                                                             L, DMODEL, FF, 0, 3, LD);
  modresid_kernel<<<(int)((LD + 255) / 256), 256, 0, stream>>>(hbuf, Pp, 3, LD, b2, outp, sst, temb, 5, FS, LD);
}